// Round 1
// baseline (1037.352 us; speedup 1.0000x reference)
//
#include <hip/hip_runtime.h>

// Problem constants (reference: B=16, NAT=256, K=24, F=128, L=4, EPS=0.01)
#define NB 16
#define NATS 256
#define KNN 24
#define FD 128
#define EPSA 0.01f
#define NATOMS (NB * NATS)      // 4096
#define NEDGE (NATOMS * KNN)    // 98304

__device__ __forceinline__ float silu_f(float v) { return v / (1.f + __expf(-v)); }

// ---------------- init: x = mod(x,1), h = emb[z], rho = geo = I ----------------
__global__ __launch_bounds__(256) void init_kernel(const float* __restrict__ xin,
    const int* __restrict__ z, const float* __restrict__ emb,
    float* __restrict__ x, float* __restrict__ h,
    float* __restrict__ rho, float* __restrict__ geo)
{
    int tid = blockIdx.x * 256 + threadIdx.x;       // grid 2048*256 = 524288 = NATOMS*FD
    int a = tid >> 7, f = tid & 127;
    h[tid] = emb[z[a] * FD + f];
    if (tid < NATOMS * 3) { float v = xin[tid]; x[tid] = v - floorf(v); }
    if (tid < 2 * NB * 9) {
        int i = tid % 9;
        float val = (i == 0 || i == 4 || i == 8) ? 1.f : 0.f;
        if (tid < NB * 9) rho[tid] = val; else geo[tid - NB * 9] = val;
    }
}

// ---------------- kNN: per-atom wave, iterative argmin (matches top_k tie-break) ----------------
__global__ __launch_bounds__(64) void knn_kernel(const float* __restrict__ x, int* __restrict__ idxb)
{
    const int a = blockIdx.x;          // global atom
    const int b = a >> 8;
    const int lane = threadIdx.x;
    const float xi0 = x[a * 3 + 0], xi1 = x[a * 3 + 1], xi2 = x[a * 3 + 2];
    unsigned long long key[4];
#pragma unroll
    for (int tt = 0; tt < 4; ++tt) {
        int jg = b * NATS + lane + tt * 64;
        float d0 = x[jg * 3 + 0] - xi0; d0 -= rintf(d0);
        float d1 = x[jg * 3 + 1] - xi1; d1 -= rintf(d1);
        float d2 = x[jg * 3 + 2] - xi2; d2 -= rintf(d2);
        float dd = sqrtf(d0 * d0 + d1 * d1 + d2 * d2);
        if (jg == a) dd += 1e6f;       // exclude self (ref adds 1e6*eye)
        key[tt] = ((unsigned long long)__float_as_uint(dd) << 32) | (unsigned)jg;
    }
    for (int sel = 0; sel < KNN; ++sel) {
        unsigned long long m = key[0];
        if (key[1] < m) m = key[1];
        if (key[2] < m) m = key[2];
        if (key[3] < m) m = key[3];
#pragma unroll
        for (int off = 32; off > 0; off >>= 1) {
            unsigned lo = (unsigned)__shfl_xor((int)(unsigned)(m & 0xffffffffu), off);
            unsigned hi = (unsigned)__shfl_xor((int)(unsigned)(m >> 32), off);
            unsigned long long o = ((unsigned long long)hi << 32) | lo;
            if (o < m) m = o;
        }
        if (lane == 0) idxb[a * KNN + sel] = (int)(m & 0xffffffffu);
#pragma unroll
        for (int tt = 0; tt < 4; ++tt) if (key[tt] == m) key[tt] = ~0ull;
    }
}

// ---------------- edges: vec = minimum-image frac @ cell, dist, u (optionally u0) ----------------
__global__ __launch_bounds__(256) void edges_kernel(const float* __restrict__ x,
    const float* __restrict__ cell, const int* __restrict__ idxb,
    float* __restrict__ vec, float* __restrict__ dist,
    float* __restrict__ u, float* __restrict__ u0, int write_u0)
{
    int e = blockIdx.x * 256 + threadIdx.x;
    if (e >= NEDGE) return;
    int a = e / KNN; int b = a >> 8;
    int j = idxb[e];
    float f0 = x[j * 3 + 0] - x[a * 3 + 0]; f0 -= rintf(f0);
    float f1 = x[j * 3 + 1] - x[a * 3 + 1]; f1 -= rintf(f1);
    float f2 = x[j * 3 + 2] - x[a * 3 + 2]; f2 -= rintf(f2);
    const float* c = cell + b * 9;
    float v0 = f0 * c[0] + f1 * c[3] + f2 * c[6];
    float v1 = f0 * c[1] + f1 * c[4] + f2 * c[7];
    float v2 = f0 * c[2] + f1 * c[5] + f2 * c[8];
    float dd = sqrtf(v0 * v0 + v1 * v1 + v2 * v2);
    vec[e * 3 + 0] = v0; vec[e * 3 + 1] = v1; vec[e * 3 + 2] = v2;
    dist[e] = dd;
    float inv = 1.f / (dd + 1e-12f);
    float a0 = v0 * inv, a1 = v1 * inv, a2 = v2 * inv;
    u[e * 3 + 0] = a0; u[e * 3 + 1] = a1; u[e * 3 + 2] = a2;
    if (write_u0) { u0[e * 3 + 0] = a0; u0[e * 3 + 1] = a1; u0[e * 3 + 2] = a2; }
}

// ---------------- GEMM1: C[4096][128] = A[4096][128] @ B[128][128] ----------------
__global__ __launch_bounds__(256) void gemm1_kernel(const float* __restrict__ A,
    const float* __restrict__ B, float* __restrict__ C)
{
    __shared__ float As[128 * 18];   // [f][m], pad to 18 (even -> b64 reads ok)
    __shared__ float Bs[64 * 128];   // half-K staging (keep LDS < 64 KB)
    const int t = threadIdx.x;
    const int tile = blockIdx.x;     // 256 tiles of 16 rows
    {
        const int r = t >> 4;
        const int f0 = (t & 15) * 8;
        const float4* src = (const float4*)(A + (tile * 16 + r) * FD + f0);
        float4 v0 = src[0], v1 = src[1];
        As[(f0 + 0) * 18 + r] = v0.x; As[(f0 + 1) * 18 + r] = v0.y;
        As[(f0 + 2) * 18 + r] = v0.z; As[(f0 + 3) * 18 + r] = v0.w;
        As[(f0 + 4) * 18 + r] = v1.x; As[(f0 + 5) * 18 + r] = v1.y;
        As[(f0 + 6) * 18 + r] = v1.z; As[(f0 + 7) * 18 + r] = v1.w;
    }
    const int ng = t & 31, mg = t >> 5;
    const int n0 = ng * 4, m0 = mg * 2;
    float a00 = 0, a01 = 0, a02 = 0, a03 = 0, a10 = 0, a11 = 0, a12 = 0, a13 = 0;
    for (int half = 0; half < 2; ++half) {
        __syncthreads();
        const float4* B4 = (const float4*)(B + half * 64 * FD);
        float4* Bs4 = (float4*)Bs;
#pragma unroll
        for (int i = 0; i < 8; ++i) Bs4[t + i * 256] = B4[t + i * 256];
        __syncthreads();
#pragma unroll 4
        for (int ff = 0; ff < 64; ++ff) {
            int f = half * 64 + ff;
            float2 av = *(const float2*)&As[f * 18 + m0];
            float4 bv = *(const float4*)&Bs[ff * FD + n0];
            a00 += av.x * bv.x; a01 += av.x * bv.y; a02 += av.x * bv.z; a03 += av.x * bv.w;
            a10 += av.y * bv.x; a11 += av.y * bv.y; a12 += av.y * bv.z; a13 += av.y * bv.w;
        }
    }
    int row = tile * 16 + m0;
    *(float4*)(C + row * FD + n0) = make_float4(a00, a01, a02, a03);
    *(float4*)(C + (row + 1) * FD + n0) = make_float4(a10, a11, a12, a13);
}

// ---------------- fused: agg over edges (silu(hW_j + d*wl + b1) summed) -> s; h += silu(s@W2+b2);
//                  optional epilogue p = h_new . act_we, q = h_new . actpos_we ----------------
__global__ __launch_bounds__(256) void gemm2_agg_kernel(
    const float* __restrict__ hW, const int* __restrict__ idxb,
    const float* __restrict__ distb,
    const float* __restrict__ wl, const float* __restrict__ b1,
    const float* __restrict__ W2, const float* __restrict__ b2,
    float* __restrict__ h,
    const float* __restrict__ we_a, const float* __restrict__ we_p,
    float* __restrict__ p, float* __restrict__ q)
{
    __shared__ float As[128 * 18];   // s transposed: [g][a]
    __shared__ float Bs[64 * 128];
    __shared__ int   sIdx[16 * KNN];
    __shared__ float sDist[16 * KNN];
    const int t = threadIdx.x;
    const int tile = blockIdx.x;
    const int atom0 = tile * 16;
    for (int e = t; e < 16 * KNN; e += 256) {
        sIdx[e] = idxb[atom0 * KNN + e];
        sDist[e] = distb[atom0 * KNN + e];
    }
    __syncthreads();
    {
        const int g = t & 127;
        const int sub = t >> 7;
        const float wlg = wl[g];
        const float b1g = b1[g];
        for (int rep = 0; rep < 8; ++rep) {
            const int a = rep * 2 + sub;
            float s = 0.f;
#pragma unroll 4
            for (int k = 0; k < KNN; ++k) {
                int j = sIdx[a * KNN + k];
                float v = hW[j * FD + g] + sDist[a * KNN + k] * wlg + b1g;
                s += silu_f(v);
            }
            As[g * 18 + a] = s;
        }
    }
    const int ng = t & 31, mg = t >> 5;
    const int n0 = ng * 4, m0 = mg * 2;
    float a00 = 0, a01 = 0, a02 = 0, a03 = 0, a10 = 0, a11 = 0, a12 = 0, a13 = 0;
    for (int half = 0; half < 2; ++half) {
        __syncthreads();
        const float4* B4 = (const float4*)(W2 + half * 64 * FD);
        float4* Bs4 = (float4*)Bs;
#pragma unroll
        for (int i = 0; i < 8; ++i) Bs4[t + i * 256] = B4[t + i * 256];
        __syncthreads();
#pragma unroll 4
        for (int ff = 0; ff < 64; ++ff) {
            int f = half * 64 + ff;
            float2 av = *(const float2*)&As[f * 18 + m0];
            float4 bv = *(const float4*)&Bs[ff * FD + n0];
            a00 += av.x * bv.x; a01 += av.x * bv.y; a02 += av.x * bv.z; a03 += av.x * bv.w;
            a10 += av.y * bv.x; a11 += av.y * bv.y; a12 += av.y * bv.z; a13 += av.y * bv.w;
        }
    }
    int row = atom0 + m0;
    float4 bb = *(const float4*)(b2 + n0);
    float4 h0 = *(float4*)(h + row * FD + n0);
    float4 h1 = *(float4*)(h + (row + 1) * FD + n0);
    float4 o0, o1;
    o0.x = h0.x + silu_f(a00 + bb.x); o0.y = h0.y + silu_f(a01 + bb.y);
    o0.z = h0.z + silu_f(a02 + bb.z); o0.w = h0.w + silu_f(a03 + bb.w);
    o1.x = h1.x + silu_f(a10 + bb.x); o1.y = h1.y + silu_f(a11 + bb.y);
    o1.z = h1.z + silu_f(a12 + bb.z); o1.w = h1.w + silu_f(a13 + bb.w);
    *(float4*)(h + row * FD + n0) = o0;
    *(float4*)(h + (row + 1) * FD + n0) = o1;
    if (we_a != nullptr) {
        float4 wa = *(const float4*)(we_a + n0);
        float4 wp = *(const float4*)(we_p + n0);
        float p0 = o0.x * wa.x + o0.y * wa.y + o0.z * wa.z + o0.w * wa.w;
        float p1 = o1.x * wa.x + o1.y * wa.y + o1.z * wa.z + o1.w * wa.w;
        float q0 = o0.x * wp.x + o0.y * wp.y + o0.z * wp.z + o0.w * wp.w;
        float q1 = o1.x * wp.x + o1.y * wp.y + o1.z * wp.z + o1.w * wp.w;
#pragma unroll
        for (int off = 16; off > 0; off >>= 1) {
            p0 += __shfl_xor(p0, off); p1 += __shfl_xor(p1, off);
            q0 += __shfl_xor(q0, off); q1 += __shfl_xor(q1, off);
        }
        if (ng == 0) { p[row] = p0; p[row + 1] = p1; q[row] = q0; q[row + 1] = q1; }
    }
}

// ---------------- per-atom action accumulation: strain/tri partials + x_cart ----------------
__global__ __launch_bounds__(64) void accum_kernel(
    const float* __restrict__ p, const float* __restrict__ q,
    const int* __restrict__ idxb, const float* __restrict__ vecb,
    const float* __restrict__ ub, const float* __restrict__ u0b,
    float* __restrict__ acc, float* __restrict__ xcart)
{
    const int a = blockIdx.x;
    const int b = a >> 8;
    const int lane = threadIdx.x;
    __shared__ float swe[KNN], swp[KNN], su[KNN][3], su0[KNN][3], sv[KNN][3];
    if (lane < KNN) {
        int e = a * KNN + lane;
        int j = idxb[e];
        swe[lane] = tanhf(p[a] + p[j]);
        swp[lane] = tanhf(q[a] + q[j]);
        su[lane][0] = ub[e * 3]; su[lane][1] = ub[e * 3 + 1]; su[lane][2] = ub[e * 3 + 2];
        su0[lane][0] = u0b[e * 3]; su0[lane][1] = u0b[e * 3 + 1]; su0[lane][2] = u0b[e * 3 + 2];
        sv[lane][0] = vecb[e * 3]; sv[lane][1] = vecb[e * 3 + 1]; sv[lane][2] = vecb[e * 3 + 2];
    }
    __syncthreads();
    float r[21];
#pragma unroll
    for (int i = 0; i < 21; ++i) r[i] = 0.f;
    if (lane < KNN) {
        float w = swe[lane];
        float ux = su[lane][0], uy = su[lane][1], uz = su[lane][2];
        r[0] = w * ux * ux; r[1] = w * ux * uy; r[2] = w * ux * uz;
        r[3] = w * uy * ux; r[4] = w * uy * uy; r[5] = w * uy * uz;
        r[6] = w * uz * ux; r[7] = w * uz * uy; r[8] = w * uz * uz;
        float wp = swp[lane];
        r[18] = wp * sv[lane][0]; r[19] = wp * sv[lane][1]; r[20] = wp * sv[lane][2];
    }
#pragma unroll
    for (int tt = 0; tt < 9; ++tt) {
        int pr = lane + (tt << 6);          // 0..575 = 24*24
        int j = pr / KNN, k = pr - j * KNN;
        // mask from initial geometry (filter_triplets)
        float c0x = su0[j][1] * su0[k][2] - su0[j][2] * su0[k][1];
        float c0y = su0[j][2] * su0[k][0] - su0[j][0] * su0[k][2];
        float c0z = su0[j][0] * su0[k][1] - su0[j][1] * su0[k][0];
        float nn = sqrtf(c0x * c0x + c0y * c0y + c0z * c0z);
        if (nn > 1e-3f) {
            float cx = su[j][1] * su[k][2] - su[j][2] * su[k][1];
            float cy = su[j][2] * su[k][0] - su[j][0] * su[k][2];
            float cz = su[j][0] * su[k][1] - su[j][1] * su[k][0];
            float w = swe[j] * swe[k];
            r[9]  += w * cx * cx; r[10] += w * cx * cy; r[11] += w * cx * cz;
            r[12] += w * cy * cx; r[13] += w * cy * cy; r[14] += w * cy * cz;
            r[15] += w * cz * cx; r[16] += w * cz * cy; r[17] += w * cz * cz;
        }
    }
#pragma unroll
    for (int off = 32; off > 0; off >>= 1)
#pragma unroll
        for (int i = 0; i < 21; ++i) r[i] += __shfl_down(r[i], off);
    if (lane == 0) {
#pragma unroll
        for (int i = 0; i < 18; ++i) atomicAdd(&acc[b * 18 + i], r[i]);
        xcart[a * 3 + 0] = EPSA * r[18];
        xcart[a * 3 + 1] = EPSA * r[19];
        xcart[a * 3 + 2] = EPSA * r[20];
    }
}

// ---------------- per-structure 3x3 chain: action, rho update, inv(old geo) ----------------
__global__ __launch_bounds__(64) void rho_kernel(const float* __restrict__ acc,
    float* __restrict__ rho, float* __restrict__ geo, float* __restrict__ invg)
{
    int b = threadIdx.x;
    if (b >= NB) return;
    const float* ac = acc + b * 18;
    float A[9];
#pragma unroll
    for (int i = 0; i < 9; ++i) {
        float strain = ac[i] / 6144.f;          // NAT*K
        float tri = ac[9 + i] / 147456.f;       // NAT*K*K
        A[i] = ((i == 0 || i == 4 || i == 8) ? 1.f : 0.f) + EPSA * (strain + tri);
    }
    float R[9], G[9];
#pragma unroll
    for (int i = 0; i < 9; ++i) { R[i] = rho[b * 9 + i]; G[i] = geo[b * 9 + i]; }
    float N[9];
#pragma unroll
    for (int i = 0; i < 3; ++i)
#pragma unroll
        for (int k = 0; k < 3; ++k)
            N[i * 3 + k] = A[i * 3 + 0] * R[0 + k] + A[i * 3 + 1] * R[3 + k] + A[i * 3 + 2] * R[6 + k];
    // inverse of old geo (used for x_frac this layer)
    float det = G[0] * (G[4] * G[8] - G[5] * G[7])
              - G[1] * (G[3] * G[8] - G[5] * G[6])
              + G[2] * (G[3] * G[7] - G[4] * G[6]);
    float id = 1.f / det;
    float IV[9];
    IV[0] = (G[4] * G[8] - G[5] * G[7]) * id;
    IV[1] = (G[2] * G[7] - G[1] * G[8]) * id;
    IV[2] = (G[1] * G[5] - G[2] * G[4]) * id;
    IV[3] = (G[5] * G[6] - G[3] * G[8]) * id;
    IV[4] = (G[0] * G[8] - G[2] * G[6]) * id;
    IV[5] = (G[2] * G[3] - G[0] * G[5]) * id;
    IV[6] = (G[3] * G[7] - G[4] * G[6]) * id;
    IV[7] = (G[1] * G[6] - G[0] * G[7]) * id;
    IV[8] = (G[0] * G[4] - G[1] * G[3]) * id;
#pragma unroll
    for (int i = 0; i < 9; ++i) {
        invg[b * 9 + i] = IV[i];
        rho[b * 9 + i] = N[i];      // rho_prime = action_rho @ I = action_rho
        geo[b * 9 + i] = N[i];
    }
}

// ---------------- position update: x += x_cart @ inv(old geo); traj += x_cart ----------------
__global__ __launch_bounds__(256) void pos_kernel(const float* __restrict__ xcart,
    const float* __restrict__ invg, float* __restrict__ x, float* __restrict__ traj)
{
    int tid = blockIdx.x * 256 + threadIdx.x;
    if (tid >= NATOMS * 3) return;
    int a = tid / 3, d = tid - a * 3, b = a >> 8;
    const float* iv = invg + b * 9;
    float c0 = xcart[a * 3 + 0], c1 = xcart[a * 3 + 1], c2 = xcart[a * 3 + 2];
    float xf = c0 * iv[0 + d] + c1 * iv[3 + d] + c2 * iv[6 + d];
    x[tid] += xf;
    traj[tid] += xcart[tid];
}

// ---------------- writeout ----------------
__global__ __launch_bounds__(256) void writeout_kernel(const float* __restrict__ traj,
    const float* __restrict__ rho, float* __restrict__ out)
{
    int tid = blockIdx.x * 256 + threadIdx.x;
    if (tid >= NATOMS * 3 + NB * 9) return;
    out[tid] = (tid < NATOMS * 3) ? traj[tid] : rho[tid - NATOMS * 3];
}

extern "C" void kernel_launch(void* const* d_in, const int* in_sizes, int n_in,
                              void* d_out, int out_size, void* d_ws, size_t ws_size,
                              hipStream_t stream)
{
    (void)in_sizes; (void)n_in; (void)out_size; (void)ws_size;
    const float* in_x = (const float*)d_in[1];
    const int*   z    = (const int*)d_in[2];
    const float* emb  = (const float*)d_in[4];
    const float* mW1  = (const float*)d_in[5];
    const float* mb1  = (const float*)d_in[6];
    const float* mW2  = (const float*)d_in[7];
    const float* mb2  = (const float*)d_in[8];
    const float* uW1  = (const float*)d_in[9];
    const float* ub1  = (const float*)d_in[10];
    const float* uW2  = (const float*)d_in[11];
    const float* ub2  = (const float*)d_in[12];
    const float* awe  = (const float*)d_in[13];
    const float* pwe  = (const float*)d_in[14];
    float* out = (float*)d_out;

    // workspace carve (~8.7 MB)
    char* wsb = (char*)d_ws;
    size_t off = 0;
    auto carve = [&](size_t elems) {
        void* ptr = wsb + off;
        off += (elems * 4 + 255) & ~(size_t)255;
        return ptr;
    };
    float* traj  = (float*)carve(NATOMS * 3);     // zeroed (must be first, contiguous with acc)
    float* acc   = (float*)carve(4 * NB * 18);    // zeroed; per-layer slices
    float* x     = (float*)carve(NATOMS * 3);
    float* xcart = (float*)carve(NATOMS * 3);
    float* p     = (float*)carve(NATOMS);
    float* q     = (float*)carve(NATOMS);
    float* rho   = (float*)carve(NB * 9);
    float* geo   = (float*)carve(NB * 9);
    float* invg  = (float*)carve(NB * 9);
    float* vec   = (float*)carve(NEDGE * 3);
    float* dist  = (float*)carve(NEDGE);
    float* u     = (float*)carve(NEDGE * 3);
    float* u0    = (float*)carve(NEDGE * 3);
    float* h     = (float*)carve(NATOMS * FD);
    float* hW    = (float*)carve(NATOMS * FD);
    int*   idx   = (int*)carve(NEDGE);

    // zero traj + acc (contiguous from ws start: 12288*4 aligned to 256 -> acc follows)
    hipMemsetAsync(traj, 0, ((size_t)NATOMS * 3 * 4 + 255 & ~(size_t)255) + 4 * NB * 18 * 4, stream);

    init_kernel<<<2048, 256, 0, stream>>>(in_x, z, emb, x, h, rho, geo);
    knn_kernel<<<NATOMS, 64, 0, stream>>>(x, idx);
    edges_kernel<<<(NEDGE + 255) / 256, 256, 0, stream>>>(x, geo, idx, vec, dist, u, u0, 1);

    // message-passing layers (initial geometry)
    for (int l = 0; l < 4; ++l) {
        gemm1_kernel<<<256, 256, 0, stream>>>(h, mW1 + l * 129 * 128, hW);
        gemm2_agg_kernel<<<256, 256, 0, stream>>>(hW, idx, dist,
            mW1 + l * 129 * 128 + 128 * 128, mb1 + l * 128,
            mW2 + l * 128 * 128, mb2 + l * 128, h,
            nullptr, nullptr, nullptr, nullptr);
    }
    // action layers
    for (int l = 0; l < 4; ++l) {
        gemm1_kernel<<<256, 256, 0, stream>>>(h, uW1 + l * 129 * 128, hW);
        gemm2_agg_kernel<<<256, 256, 0, stream>>>(hW, idx, dist,
            uW1 + l * 129 * 128 + 128 * 128, ub1 + l * 128,
            uW2 + l * 128 * 128, ub2 + l * 128, h,
            awe + l * 128, pwe + l * 128, p, q);
        accum_kernel<<<NATOMS, 64, 0, stream>>>(p, q, idx, vec, u, u0,
            acc + l * NB * 18, xcart);
        rho_kernel<<<1, 64, 0, stream>>>(acc + l * NB * 18, rho, geo, invg);
        pos_kernel<<<(NATOMS * 3 + 255) / 256, 256, 0, stream>>>(xcart, invg, x, traj);
        if (l < 3)
            edges_kernel<<<(NEDGE + 255) / 256, 256, 0, stream>>>(x, geo, idx, vec, dist, u, u0, 0);
    }
    writeout_kernel<<<(NATOMS * 3 + NB * 9 + 255) / 256, 256, 0, stream>>>(traj, rho, out);
}

// Round 2
// 477.435 us; speedup vs baseline: 2.1728x; 2.1728x over previous
//
#include <hip/hip_runtime.h>

// Problem constants (reference: B=16, NAT=256, K=24, F=128, L=4, EPS=0.01)
#define NB 16
#define NATS 256
#define KNN 24
#define FD 128
#define EPSA 0.01f
#define NATOMS (NB * NATS)      // 4096
#define NEDGE (NATOMS * KNN)    // 98304

__device__ __forceinline__ float silu_f(float v) { return v / (1.f + __expf(-v)); }

// ---------------- init: x = mod(x,1), h = emb[z], rho = geo = I ----------------
__global__ __launch_bounds__(256) void init_kernel(const float* __restrict__ xin,
    const int* __restrict__ z, const float* __restrict__ emb,
    float* __restrict__ x, float* __restrict__ h,
    float* __restrict__ rho, float* __restrict__ geo)
{
    int tid = blockIdx.x * 256 + threadIdx.x;       // grid 2048*256 = 524288 = NATOMS*FD
    int a = tid >> 7, f = tid & 127;
    h[tid] = emb[z[a] * FD + f];
    if (tid < NATOMS * 3) { float v = xin[tid]; x[tid] = v - floorf(v); }
    if (tid < 2 * NB * 9) {
        int i = tid % 9;
        float val = (i == 0 || i == 4 || i == 8) ? 1.f : 0.f;
        if (tid < NB * 9) rho[tid] = val; else geo[tid - NB * 9] = val;
    }
}

// ---------------- kNN: per-atom wave, iterative argmin (matches top_k tie-break) ----------------
__global__ __launch_bounds__(64) void knn_kernel(const float* __restrict__ x, int* __restrict__ idxb)
{
    const int a = blockIdx.x;          // global atom
    const int b = a >> 8;
    const int lane = threadIdx.x;
    const float xi0 = x[a * 3 + 0], xi1 = x[a * 3 + 1], xi2 = x[a * 3 + 2];
    unsigned long long key[4];
#pragma unroll
    for (int tt = 0; tt < 4; ++tt) {
        int jg = b * NATS + lane + tt * 64;
        float d0 = x[jg * 3 + 0] - xi0; d0 -= rintf(d0);
        float d1 = x[jg * 3 + 1] - xi1; d1 -= rintf(d1);
        float d2 = x[jg * 3 + 2] - xi2; d2 -= rintf(d2);
        float dd = sqrtf(d0 * d0 + d1 * d1 + d2 * d2);
        if (jg == a) dd += 1e6f;       // exclude self (ref adds 1e6*eye)
        key[tt] = ((unsigned long long)__float_as_uint(dd) << 32) | (unsigned)jg;
    }
    for (int sel = 0; sel < KNN; ++sel) {
        unsigned long long m = key[0];
        if (key[1] < m) m = key[1];
        if (key[2] < m) m = key[2];
        if (key[3] < m) m = key[3];
#pragma unroll
        for (int off = 32; off > 0; off >>= 1) {
            unsigned lo = (unsigned)__shfl_xor((int)(unsigned)(m & 0xffffffffu), off);
            unsigned hi = (unsigned)__shfl_xor((int)(unsigned)(m >> 32), off);
            unsigned long long o = ((unsigned long long)hi << 32) | lo;
            if (o < m) m = o;
        }
        if (lane == 0) idxb[a * KNN + sel] = (int)(m & 0xffffffffu);
#pragma unroll
        for (int tt = 0; tt < 4; ++tt) if (key[tt] == m) key[tt] = ~0ull;
    }
}

// ---------------- edges: vec = minimum-image frac @ cell, dist, u (optionally u0) ----------------
__global__ __launch_bounds__(256) void edges_kernel(const float* __restrict__ x,
    const float* __restrict__ cell, const int* __restrict__ idxb,
    float* __restrict__ vec, float* __restrict__ dist,
    float* __restrict__ u, float* __restrict__ u0, int write_u0)
{
    int e = blockIdx.x * 256 + threadIdx.x;
    if (e >= NEDGE) return;
    int a = e / KNN; int b = a >> 8;
    int j = idxb[e];
    float f0 = x[j * 3 + 0] - x[a * 3 + 0]; f0 -= rintf(f0);
    float f1 = x[j * 3 + 1] - x[a * 3 + 1]; f1 -= rintf(f1);
    float f2 = x[j * 3 + 2] - x[a * 3 + 2]; f2 -= rintf(f2);
    const float* c = cell + b * 9;
    float v0 = f0 * c[0] + f1 * c[3] + f2 * c[6];
    float v1 = f0 * c[1] + f1 * c[4] + f2 * c[7];
    float v2 = f0 * c[2] + f1 * c[5] + f2 * c[8];
    float dd = sqrtf(v0 * v0 + v1 * v1 + v2 * v2);
    vec[e * 3 + 0] = v0; vec[e * 3 + 1] = v1; vec[e * 3 + 2] = v2;
    dist[e] = dd;
    float inv = 1.f / (dd + 1e-12f);
    float a0 = v0 * inv, a1 = v1 * inv, a2 = v2 * inv;
    u[e * 3 + 0] = a0; u[e * 3 + 1] = a1; u[e * 3 + 2] = a2;
    if (write_u0) { u0[e * 3 + 0] = a0; u0[e * 3 + 1] = a1; u0[e * 3 + 2] = a2; }
}

// ---------------- GEMM1: C[4096][128] = A[4096][128] @ B[128][128] ----------------
__global__ __launch_bounds__(256) void gemm1_kernel(const float* __restrict__ A,
    const float* __restrict__ B, float* __restrict__ C)
{
    __shared__ float As[128 * 18];   // [f][m], pad to 18 (even -> b64 reads ok)
    __shared__ float Bs[64 * 128];   // half-K staging (keep LDS < 64 KB)
    const int t = threadIdx.x;
    const int tile = blockIdx.x;     // 256 tiles of 16 rows
    {
        const int r = t >> 4;
        const int f0 = (t & 15) * 8;
        const float4* src = (const float4*)(A + (tile * 16 + r) * FD + f0);
        float4 v0 = src[0], v1 = src[1];
        As[(f0 + 0) * 18 + r] = v0.x; As[(f0 + 1) * 18 + r] = v0.y;
        As[(f0 + 2) * 18 + r] = v0.z; As[(f0 + 3) * 18 + r] = v0.w;
        As[(f0 + 4) * 18 + r] = v1.x; As[(f0 + 5) * 18 + r] = v1.y;
        As[(f0 + 6) * 18 + r] = v1.z; As[(f0 + 7) * 18 + r] = v1.w;
    }
    const int ng = t & 31, mg = t >> 5;
    const int n0 = ng * 4, m0 = mg * 2;
    float a00 = 0, a01 = 0, a02 = 0, a03 = 0, a10 = 0, a11 = 0, a12 = 0, a13 = 0;
    for (int half = 0; half < 2; ++half) {
        __syncthreads();
        const float4* B4 = (const float4*)(B + half * 64 * FD);
        float4* Bs4 = (float4*)Bs;
#pragma unroll
        for (int i = 0; i < 8; ++i) Bs4[t + i * 256] = B4[t + i * 256];
        __syncthreads();
#pragma unroll 4
        for (int ff = 0; ff < 64; ++ff) {
            int f = half * 64 + ff;
            float2 av = *(const float2*)&As[f * 18 + m0];
            float4 bv = *(const float4*)&Bs[ff * FD + n0];
            a00 += av.x * bv.x; a01 += av.x * bv.y; a02 += av.x * bv.z; a03 += av.x * bv.w;
            a10 += av.y * bv.x; a11 += av.y * bv.y; a12 += av.y * bv.z; a13 += av.y * bv.w;
        }
    }
    int row = tile * 16 + m0;
    *(float4*)(C + row * FD + n0) = make_float4(a00, a01, a02, a03);
    *(float4*)(C + (row + 1) * FD + n0) = make_float4(a10, a11, a12, a13);
}

// ---------------- fused: agg over edges (silu(hW_j + d*wl + b1) summed) -> s; h += silu(s@W2+b2);
//                  optional epilogue p = h_new . act_we, q = h_new . actpos_we ----------------
__global__ __launch_bounds__(256) void gemm2_agg_kernel(
    const float* __restrict__ hW, const int* __restrict__ idxb,
    const float* __restrict__ distb,
    const float* __restrict__ wl, const float* __restrict__ b1,
    const float* __restrict__ W2, const float* __restrict__ b2,
    float* __restrict__ h,
    const float* __restrict__ we_a, const float* __restrict__ we_p,
    float* __restrict__ p, float* __restrict__ q)
{
    __shared__ float As[128 * 18];   // s transposed: [g][a]
    __shared__ float Bs[64 * 128];
    __shared__ int   sIdx[16 * KNN];
    __shared__ float sDist[16 * KNN];
    const int t = threadIdx.x;
    const int tile = blockIdx.x;
    const int atom0 = tile * 16;
    for (int e = t; e < 16 * KNN; e += 256) {
        sIdx[e] = idxb[atom0 * KNN + e];
        sDist[e] = distb[atom0 * KNN + e];
    }
    __syncthreads();
    {
        const int g = t & 127;
        const int sub = t >> 7;
        const float wlg = wl[g];
        const float b1g = b1[g];
        for (int rep = 0; rep < 8; ++rep) {
            const int a = rep * 2 + sub;
            float s = 0.f;
#pragma unroll 4
            for (int k = 0; k < KNN; ++k) {
                int j = sIdx[a * KNN + k];
                float v = hW[j * FD + g] + sDist[a * KNN + k] * wlg + b1g;
                s += silu_f(v);
            }
            As[g * 18 + a] = s;
        }
    }
    const int ng = t & 31, mg = t >> 5;
    const int n0 = ng * 4, m0 = mg * 2;
    float a00 = 0, a01 = 0, a02 = 0, a03 = 0, a10 = 0, a11 = 0, a12 = 0, a13 = 0;
    for (int half = 0; half < 2; ++half) {
        __syncthreads();
        const float4* B4 = (const float4*)(W2 + half * 64 * FD);
        float4* Bs4 = (float4*)Bs;
#pragma unroll
        for (int i = 0; i < 8; ++i) Bs4[t + i * 256] = B4[t + i * 256];
        __syncthreads();
#pragma unroll 4
        for (int ff = 0; ff < 64; ++ff) {
            int f = half * 64 + ff;
            float2 av = *(const float2*)&As[f * 18 + m0];
            float4 bv = *(const float4*)&Bs[ff * FD + n0];
            a00 += av.x * bv.x; a01 += av.x * bv.y; a02 += av.x * bv.z; a03 += av.x * bv.w;
            a10 += av.y * bv.x; a11 += av.y * bv.y; a12 += av.y * bv.z; a13 += av.y * bv.w;
        }
    }
    int row = atom0 + m0;
    float4 bb = *(const float4*)(b2 + n0);
    float4 h0 = *(float4*)(h + row * FD + n0);
    float4 h1 = *(float4*)(h + (row + 1) * FD + n0);
    float4 o0, o1;
    o0.x = h0.x + silu_f(a00 + bb.x); o0.y = h0.y + silu_f(a01 + bb.y);
    o0.z = h0.z + silu_f(a02 + bb.z); o0.w = h0.w + silu_f(a03 + bb.w);
    o1.x = h1.x + silu_f(a10 + bb.x); o1.y = h1.y + silu_f(a11 + bb.y);
    o1.z = h1.z + silu_f(a12 + bb.z); o1.w = h1.w + silu_f(a13 + bb.w);
    *(float4*)(h + row * FD + n0) = o0;
    *(float4*)(h + (row + 1) * FD + n0) = o1;
    if (we_a != nullptr) {
        float4 wa = *(const float4*)(we_a + n0);
        float4 wp = *(const float4*)(we_p + n0);
        float p0 = o0.x * wa.x + o0.y * wa.y + o0.z * wa.z + o0.w * wa.w;
        float p1 = o1.x * wa.x + o1.y * wa.y + o1.z * wa.z + o1.w * wa.w;
        float q0 = o0.x * wp.x + o0.y * wp.y + o0.z * wp.z + o0.w * wp.w;
        float q1 = o1.x * wp.x + o1.y * wp.y + o1.z * wp.z + o1.w * wp.w;
#pragma unroll
        for (int off = 16; off > 0; off >>= 1) {
            p0 += __shfl_xor(p0, off); p1 += __shfl_xor(p1, off);
            q0 += __shfl_xor(q0, off); q1 += __shfl_xor(q1, off);
        }
        if (ng == 0) { p[row] = p0; p[row + 1] = p1; q[row] = q0; q[row + 1] = q1; }
    }
}

// ---------------- per-atom action accumulation: strain/tri partials + x_cart ----------------
// 1024 blocks x 256 threads; wave w handles atom blk*4+w. NO atomics: per-block
// 18-float partial written to part[blk*18..]; reduced later in rho_kernel.
__global__ __launch_bounds__(256) void accum_kernel(
    const float* __restrict__ p, const float* __restrict__ q,
    const int* __restrict__ idxb, const float* __restrict__ vecb,
    const float* __restrict__ ub, const float* __restrict__ u0b,
    float* __restrict__ part, float* __restrict__ xcart)
{
    const int blk = blockIdx.x;
    const int t = threadIdx.x;
    const int w = t >> 6;
    const int lane = t & 63;
    const int a = blk * 4 + w;
    __shared__ float swe[4][KNN], swp[4][KNN];
    __shared__ float su[4][KNN][3], su0[4][KNN][3], sv[4][KNN][3];
    __shared__ float spart[4][18];
    if (lane < KNN) {
        int e = a * KNN + lane;
        int j = idxb[e];
        swe[w][lane] = tanhf(p[a] + p[j]);
        swp[w][lane] = tanhf(q[a] + q[j]);
        su[w][lane][0] = ub[e * 3]; su[w][lane][1] = ub[e * 3 + 1]; su[w][lane][2] = ub[e * 3 + 2];
        su0[w][lane][0] = u0b[e * 3]; su0[w][lane][1] = u0b[e * 3 + 1]; su0[w][lane][2] = u0b[e * 3 + 2];
        sv[w][lane][0] = vecb[e * 3]; sv[w][lane][1] = vecb[e * 3 + 1]; sv[w][lane][2] = vecb[e * 3 + 2];
    }
    __syncthreads();
    float r[21];
#pragma unroll
    for (int i = 0; i < 21; ++i) r[i] = 0.f;
    if (lane < KNN) {
        float wgt = swe[w][lane];
        float ux = su[w][lane][0], uy = su[w][lane][1], uz = su[w][lane][2];
        r[0] = wgt * ux * ux; r[1] = wgt * ux * uy; r[2] = wgt * ux * uz;
        r[3] = wgt * uy * ux; r[4] = wgt * uy * uy; r[5] = wgt * uy * uz;
        r[6] = wgt * uz * ux; r[7] = wgt * uz * uy; r[8] = wgt * uz * uz;
        float wp = swp[w][lane];
        r[18] = wp * sv[w][lane][0]; r[19] = wp * sv[w][lane][1]; r[20] = wp * sv[w][lane][2];
    }
#pragma unroll
    for (int tt = 0; tt < 9; ++tt) {
        int pr = lane + (tt << 6);          // 0..575 = 24*24
        int j = pr / KNN, k = pr - j * KNN;
        // mask from initial geometry (filter_triplets): ||u0_j x u0_k|| > 1e-3
        float c0x = su0[w][j][1] * su0[w][k][2] - su0[w][j][2] * su0[w][k][1];
        float c0y = su0[w][j][2] * su0[w][k][0] - su0[w][j][0] * su0[w][k][2];
        float c0z = su0[w][j][0] * su0[w][k][1] - su0[w][j][1] * su0[w][k][0];
        float nn2 = c0x * c0x + c0y * c0y + c0z * c0z;
        if (nn2 > 1e-6f) {
            float cx = su[w][j][1] * su[w][k][2] - su[w][j][2] * su[w][k][1];
            float cy = su[w][j][2] * su[w][k][0] - su[w][j][0] * su[w][k][2];
            float cz = su[w][j][0] * su[w][k][1] - su[w][j][1] * su[w][k][0];
            float wt = swe[w][j] * swe[w][k];
            r[9]  += wt * cx * cx; r[10] += wt * cx * cy; r[11] += wt * cx * cz;
            r[12] += wt * cy * cx; r[13] += wt * cy * cy; r[14] += wt * cy * cz;
            r[15] += wt * cz * cx; r[16] += wt * cz * cy; r[17] += wt * cz * cz;
        }
    }
#pragma unroll
    for (int off = 32; off > 0; off >>= 1)
#pragma unroll
        for (int i = 0; i < 21; ++i) r[i] += __shfl_down(r[i], off);
    if (lane == 0) {
#pragma unroll
        for (int i = 0; i < 18; ++i) spart[w][i] = r[i];
        xcart[a * 3 + 0] = EPSA * r[18];
        xcart[a * 3 + 1] = EPSA * r[19];
        xcart[a * 3 + 2] = EPSA * r[20];
    }
    __syncthreads();
    if (t < 18)
        part[blk * 18 + t] = spart[0][t] + spart[1][t] + spart[2][t] + spart[3][t];
}

// ---------------- per-structure: reduce partials; 3x3 chain: action, rho update, inv(old geo) ----------------
// grid 16 blocks (one per structure) x 64 lanes; 64 block-partials per structure.
__global__ __launch_bounds__(64) void rho_kernel(const float* __restrict__ part,
    float* __restrict__ rho, float* __restrict__ geo, float* __restrict__ invg)
{
    const int b = blockIdx.x;
    const int lane = threadIdx.x;
    float r[18];
#pragma unroll
    for (int i = 0; i < 18; ++i) r[i] = part[(b * 64 + lane) * 18 + i];
#pragma unroll
    for (int off = 32; off > 0; off >>= 1)
#pragma unroll
        for (int i = 0; i < 18; ++i) r[i] += __shfl_down(r[i], off);
    if (lane != 0) return;
    float A[9];
#pragma unroll
    for (int i = 0; i < 9; ++i) {
        float strain = r[i] / 6144.f;           // NAT*K
        float tri = r[9 + i] / 147456.f;        // NAT*K*K
        A[i] = ((i == 0 || i == 4 || i == 8) ? 1.f : 0.f) + EPSA * (strain + tri);
    }
    float R[9], G[9];
#pragma unroll
    for (int i = 0; i < 9; ++i) { R[i] = rho[b * 9 + i]; G[i] = geo[b * 9 + i]; }
    float N[9];
#pragma unroll
    for (int i = 0; i < 3; ++i)
#pragma unroll
        for (int k = 0; k < 3; ++k)
            N[i * 3 + k] = A[i * 3 + 0] * R[0 + k] + A[i * 3 + 1] * R[3 + k] + A[i * 3 + 2] * R[6 + k];
    float det = G[0] * (G[4] * G[8] - G[5] * G[7])
              - G[1] * (G[3] * G[8] - G[5] * G[6])
              + G[2] * (G[3] * G[7] - G[4] * G[6]);
    float id = 1.f / det;
    float IV[9];
    IV[0] = (G[4] * G[8] - G[5] * G[7]) * id;
    IV[1] = (G[2] * G[7] - G[1] * G[8]) * id;
    IV[2] = (G[1] * G[5] - G[2] * G[4]) * id;
    IV[3] = (G[5] * G[6] - G[3] * G[8]) * id;
    IV[4] = (G[0] * G[8] - G[2] * G[6]) * id;
    IV[5] = (G[2] * G[3] - G[0] * G[5]) * id;
    IV[6] = (G[3] * G[7] - G[4] * G[6]) * id;
    IV[7] = (G[1] * G[6] - G[0] * G[7]) * id;
    IV[8] = (G[0] * G[4] - G[1] * G[3]) * id;
#pragma unroll
    for (int i = 0; i < 9; ++i) {
        invg[b * 9 + i] = IV[i];
        rho[b * 9 + i] = N[i];      // rho_prime = action_rho @ I = action_rho
        geo[b * 9 + i] = N[i];
    }
}

// ---------------- position update: x += x_cart @ inv(old geo); traj += x_cart ----------------
__global__ __launch_bounds__(256) void pos_kernel(const float* __restrict__ xcart,
    const float* __restrict__ invg, float* __restrict__ x, float* __restrict__ traj)
{
    int tid = blockIdx.x * 256 + threadIdx.x;
    if (tid >= NATOMS * 3) return;
    int a = tid / 3, d = tid - a * 3, b = a >> 8;
    const float* iv = invg + b * 9;
    float c0 = xcart[a * 3 + 0], c1 = xcart[a * 3 + 1], c2 = xcart[a * 3 + 2];
    float xf = c0 * iv[0 + d] + c1 * iv[3 + d] + c2 * iv[6 + d];
    x[tid] += xf;
    traj[tid] += xcart[tid];
}

// ---------------- writeout ----------------
__global__ __launch_bounds__(256) void writeout_kernel(const float* __restrict__ traj,
    const float* __restrict__ rho, float* __restrict__ out)
{
    int tid = blockIdx.x * 256 + threadIdx.x;
    if (tid >= NATOMS * 3 + NB * 9) return;
    out[tid] = (tid < NATOMS * 3) ? traj[tid] : rho[tid - NATOMS * 3];
}

extern "C" void kernel_launch(void* const* d_in, const int* in_sizes, int n_in,
                              void* d_out, int out_size, void* d_ws, size_t ws_size,
                              hipStream_t stream)
{
    (void)in_sizes; (void)n_in; (void)out_size; (void)ws_size;
    const float* in_x = (const float*)d_in[1];
    const int*   z    = (const int*)d_in[2];
    const float* emb  = (const float*)d_in[4];
    const float* mW1  = (const float*)d_in[5];
    const float* mb1  = (const float*)d_in[6];
    const float* mW2  = (const float*)d_in[7];
    const float* mb2  = (const float*)d_in[8];
    const float* uW1  = (const float*)d_in[9];
    const float* ub1  = (const float*)d_in[10];
    const float* uW2  = (const float*)d_in[11];
    const float* ub2  = (const float*)d_in[12];
    const float* awe  = (const float*)d_in[13];
    const float* pwe  = (const float*)d_in[14];
    float* out = (float*)d_out;

    // workspace carve
    char* wsb = (char*)d_ws;
    size_t off = 0;
    auto carve = [&](size_t elems) {
        void* ptr = wsb + off;
        off += (elems * 4 + 255) & ~(size_t)255;
        return ptr;
    };
    float* traj  = (float*)carve(NATOMS * 3);     // zeroed below
    float* part  = (float*)carve(1024 * 18);      // per-block partials (no zero needed)
    float* x     = (float*)carve(NATOMS * 3);
    float* xcart = (float*)carve(NATOMS * 3);
    float* p     = (float*)carve(NATOMS);
    float* q     = (float*)carve(NATOMS);
    float* rho   = (float*)carve(NB * 9);
    float* geo   = (float*)carve(NB * 9);
    float* invg  = (float*)carve(NB * 9);
    float* vec   = (float*)carve(NEDGE * 3);
    float* dist  = (float*)carve(NEDGE);
    float* u     = (float*)carve(NEDGE * 3);
    float* u0    = (float*)carve(NEDGE * 3);
    float* h     = (float*)carve(NATOMS * FD);
    float* hW    = (float*)carve(NATOMS * FD);
    int*   idx   = (int*)carve(NEDGE);

    hipMemsetAsync(traj, 0, (size_t)NATOMS * 3 * 4, stream);

    init_kernel<<<2048, 256, 0, stream>>>(in_x, z, emb, x, h, rho, geo);
    knn_kernel<<<NATOMS, 64, 0, stream>>>(x, idx);
    edges_kernel<<<(NEDGE + 255) / 256, 256, 0, stream>>>(x, geo, idx, vec, dist, u, u0, 1);

    // message-passing layers (initial geometry)
    for (int l = 0; l < 4; ++l) {
        gemm1_kernel<<<256, 256, 0, stream>>>(h, mW1 + l * 129 * 128, hW);
        gemm2_agg_kernel<<<256, 256, 0, stream>>>(hW, idx, dist,
            mW1 + l * 129 * 128 + 128 * 128, mb1 + l * 128,
            mW2 + l * 128 * 128, mb2 + l * 128, h,
            nullptr, nullptr, nullptr, nullptr);
    }
    // action layers
    for (int l = 0; l < 4; ++l) {
        gemm1_kernel<<<256, 256, 0, stream>>>(h, uW1 + l * 129 * 128, hW);
        gemm2_agg_kernel<<<256, 256, 0, stream>>>(hW, idx, dist,
            uW1 + l * 129 * 128 + 128 * 128, ub1 + l * 128,
            uW2 + l * 128 * 128, ub2 + l * 128, h,
            awe + l * 128, pwe + l * 128, p, q);
        accum_kernel<<<1024, 256, 0, stream>>>(p, q, idx, vec, u, u0, part, xcart);
        rho_kernel<<<16, 64, 0, stream>>>(part, rho, geo, invg);
        pos_kernel<<<(NATOMS * 3 + 255) / 256, 256, 0, stream>>>(xcart, invg, x, traj);
        if (l < 3)
            edges_kernel<<<(NEDGE + 255) / 256, 256, 0, stream>>>(x, geo, idx, vec, dist, u, u0, 0);
    }
    writeout_kernel<<<(NATOMS * 3 + NB * 9 + 255) / 256, 256, 0, stream>>>(traj, rho, out);
}

// Round 3
// 439.616 us; speedup vs baseline: 2.3597x; 1.0860x over previous
//
#include <hip/hip_runtime.h>

// Problem constants (reference: B=16, NAT=256, K=24, F=128, L=4, EPS=0.01)
#define NB 16
#define NATS 256
#define KNN 24
#define FD 128
#define EPSA 0.01f
#define NATOMS (NB * NATS)      // 4096
#define NEDGE (NATOMS * KNN)    // 98304

__device__ __forceinline__ float silu_f(float v) { return v / (1.f + __expf(-v)); }

// ---------------- init: x = mod(x,1), h = emb[z], traj = 0 ----------------
__global__ __launch_bounds__(256) void init_kernel(const float* __restrict__ xin,
    const int* __restrict__ z, const float* __restrict__ emb,
    float* __restrict__ x, float* __restrict__ h, float* __restrict__ traj)
{
    int tid = blockIdx.x * 256 + threadIdx.x;       // grid 2048*256 = 524288 = NATOMS*FD
    int a = tid >> 7, f = tid & 127;
    h[tid] = emb[z[a] * FD + f];
    if (tid < NATOMS * 3) {
        float v = xin[tid];
        x[tid] = v - floorf(v);
        traj[tid] = 0.f;
    }
}

// ---------------- kNN: per-atom wave, iterative argmin (matches top_k tie-break) ----------------
// Epilogue: lanes 0..23 write u0 (unit edge vectors under identity cell) for triplet mask.
__global__ __launch_bounds__(64) void knn_kernel(const float* __restrict__ x,
    int* __restrict__ idxb, float* __restrict__ u0)
{
    const int a = blockIdx.x;          // global atom
    const int b = a >> 8;
    const int lane = threadIdx.x;
    const float xi0 = x[a * 3 + 0], xi1 = x[a * 3 + 1], xi2 = x[a * 3 + 2];
    unsigned long long key[4];
#pragma unroll
    for (int tt = 0; tt < 4; ++tt) {
        int jg = b * NATS + lane + tt * 64;
        float d0 = x[jg * 3 + 0] - xi0; d0 -= rintf(d0);
        float d1 = x[jg * 3 + 1] - xi1; d1 -= rintf(d1);
        float d2 = x[jg * 3 + 2] - xi2; d2 -= rintf(d2);
        float dd = sqrtf(d0 * d0 + d1 * d1 + d2 * d2);
        if (jg == a) dd += 1e6f;       // exclude self (ref adds 1e6*eye)
        key[tt] = ((unsigned long long)__float_as_uint(dd) << 32) | (unsigned)jg;
    }
    int myj = 0;
    for (int sel = 0; sel < KNN; ++sel) {
        unsigned long long m = key[0];
        if (key[1] < m) m = key[1];
        if (key[2] < m) m = key[2];
        if (key[3] < m) m = key[3];
#pragma unroll
        for (int off = 32; off > 0; off >>= 1) {
            unsigned lo = (unsigned)__shfl_xor((int)(unsigned)(m & 0xffffffffu), off);
            unsigned hi = (unsigned)__shfl_xor((int)(unsigned)(m >> 32), off);
            unsigned long long o = ((unsigned long long)hi << 32) | lo;
            if (o < m) m = o;
        }
        int jw = (int)(m & 0xffffffffu);
        if (lane == 0) idxb[a * KNN + sel] = jw;
        if (lane == sel) myj = jw;
#pragma unroll
        for (int tt = 0; tt < 4; ++tt) if (key[tt] == m) key[tt] = ~0ull;
    }
    if (lane < KNN) {
        float f0 = x[myj * 3 + 0] - xi0; f0 -= rintf(f0);
        float f1 = x[myj * 3 + 1] - xi1; f1 -= rintf(f1);
        float f2 = x[myj * 3 + 2] - xi2; f2 -= rintf(f2);
        float dd = sqrtf(f0 * f0 + f1 * f1 + f2 * f2);
        float inv = 1.f / (dd + 1e-12f);
        int e = a * KNN + lane;
        u0[e * 3 + 0] = f0 * inv; u0[e * 3 + 1] = f1 * inv; u0[e * 3 + 2] = f2 * inv;
    }
}

// ---------------- GEMM1 (only for layer 0 input): hW = h @ W1[:128] ----------------
__global__ __launch_bounds__(256) void gemm1_kernel(const float* __restrict__ A,
    const float* __restrict__ B, float* __restrict__ C)
{
    __shared__ float As[128 * 18];   // [f][m]
    __shared__ float Bs[64 * 128];
    const int t = threadIdx.x;
    const int tile = blockIdx.x;     // 256 tiles of 16 rows
    {
        const int r = t >> 4;
        const int f0 = (t & 15) * 8;
        const float4* src = (const float4*)(A + (tile * 16 + r) * FD + f0);
        float4 v0 = src[0], v1 = src[1];
        As[(f0 + 0) * 18 + r] = v0.x; As[(f0 + 1) * 18 + r] = v0.y;
        As[(f0 + 2) * 18 + r] = v0.z; As[(f0 + 3) * 18 + r] = v0.w;
        As[(f0 + 4) * 18 + r] = v1.x; As[(f0 + 5) * 18 + r] = v1.y;
        As[(f0 + 6) * 18 + r] = v1.z; As[(f0 + 7) * 18 + r] = v1.w;
    }
    const int ng = t & 31, mg = t >> 5;
    const int n0 = ng * 4, m0 = mg * 2;
    float a00 = 0, a01 = 0, a02 = 0, a03 = 0, a10 = 0, a11 = 0, a12 = 0, a13 = 0;
    for (int half = 0; half < 2; ++half) {
        __syncthreads();
        const float4* B4 = (const float4*)(B + half * 64 * FD);
        float4* Bs4 = (float4*)Bs;
#pragma unroll
        for (int i = 0; i < 8; ++i) Bs4[t + i * 256] = B4[t + i * 256];
        __syncthreads();
#pragma unroll 4
        for (int ff = 0; ff < 64; ++ff) {
            int f = half * 64 + ff;
            float2 av = *(const float2*)&As[f * 18 + m0];
            float4 bv = *(const float4*)&Bs[ff * FD + n0];
            a00 += av.x * bv.x; a01 += av.x * bv.y; a02 += av.x * bv.z; a03 += av.x * bv.w;
            a10 += av.y * bv.x; a11 += av.y * bv.y; a12 += av.y * bv.z; a13 += av.y * bv.w;
        }
    }
    int row = tile * 16 + m0;
    *(float4*)(C + row * FD + n0) = make_float4(a00, a01, a02, a03);
    *(float4*)(C + (row + 1) * FD + n0) = make_float4(a10, a11, a12, a13);
}

// ---------------- fused layer: inline dist + agg + W2 GEMM + residual (+pq) + next W1 GEMM ----------------
// block = 16 atoms (all in one structure), 256 threads.
__global__ __launch_bounds__(256) void layer_kernel(
    const float* __restrict__ hW, const int* __restrict__ idxb,
    const float* __restrict__ x, const float* __restrict__ geo, int use_geo,
    const float* __restrict__ wl, const float* __restrict__ b1,
    const float* __restrict__ W2, const float* __restrict__ b2,
    const float* __restrict__ W1n, float* __restrict__ hWout,
    float* __restrict__ h,
    const float* __restrict__ we_a, const float* __restrict__ we_p,
    float* __restrict__ p, float* __restrict__ q)
{
    __shared__ float As[128 * 18];   // s (agg output) transposed [g][a]
    __shared__ float sH[128 * 18];   // h_new transposed [g][a]
    __shared__ float Bs[64 * 128];
    __shared__ int   sIdx[16 * KNN];
    __shared__ float sDist[16 * KNN];
    const int t = threadIdx.x;
    const int atom0 = blockIdx.x * 16;
    // phase 1: indices + inline distances under current geometry
    for (int e = t; e < 16 * KNN; e += 256) {
        int a = atom0 + (e / KNN);
        int j = idxb[atom0 * KNN + e];
        sIdx[e] = j;
        float f0 = x[j * 3 + 0] - x[a * 3 + 0]; f0 -= rintf(f0);
        float f1 = x[j * 3 + 1] - x[a * 3 + 1]; f1 -= rintf(f1);
        float f2 = x[j * 3 + 2] - x[a * 3 + 2]; f2 -= rintf(f2);
        float v0 = f0, v1 = f1, v2 = f2;
        if (use_geo) {
            const float* c = geo + (a >> 8) * 9;
            v0 = f0 * c[0] + f1 * c[3] + f2 * c[6];
            v1 = f0 * c[1] + f1 * c[4] + f2 * c[7];
            v2 = f0 * c[2] + f1 * c[5] + f2 * c[8];
        }
        sDist[e] = sqrtf(v0 * v0 + v1 * v1 + v2 * v2);
    }
    __syncthreads();
    // phase 2: agg s_a[g] = sum_k silu(hW[j][g] + d*wl[g] + b1[g])
    {
        const int g = t & 127;
        const int sub = t >> 7;
        const float wlg = wl[g];
        const float b1g = b1[g];
        for (int rep = 0; rep < 8; ++rep) {
            const int a = rep * 2 + sub;
            float s = 0.f;
#pragma unroll 4
            for (int k = 0; k < KNN; ++k) {
                int j = sIdx[a * KNN + k];
                float v = hW[j * FD + g] + sDist[a * KNN + k] * wlg + b1g;
                s += silu_f(v);
            }
            As[g * 18 + a] = s;
        }
    }
    // phase 3: W2 GEMM, residual, h write
    const int ng = t & 31, mg = t >> 5;
    const int n0 = ng * 4, m0 = mg * 2;
    float a00 = 0, a01 = 0, a02 = 0, a03 = 0, a10 = 0, a11 = 0, a12 = 0, a13 = 0;
    for (int half = 0; half < 2; ++half) {
        __syncthreads();
        const float4* B4 = (const float4*)(W2 + half * 64 * FD);
        float4* Bs4 = (float4*)Bs;
#pragma unroll
        for (int i = 0; i < 8; ++i) Bs4[t + i * 256] = B4[t + i * 256];
        __syncthreads();
#pragma unroll 4
        for (int ff = 0; ff < 64; ++ff) {
            int f = half * 64 + ff;
            float2 av = *(const float2*)&As[f * 18 + m0];
            float4 bv = *(const float4*)&Bs[ff * FD + n0];
            a00 += av.x * bv.x; a01 += av.x * bv.y; a02 += av.x * bv.z; a03 += av.x * bv.w;
            a10 += av.y * bv.x; a11 += av.y * bv.y; a12 += av.y * bv.z; a13 += av.y * bv.w;
        }
    }
    int row = atom0 + m0;
    float4 bb = *(const float4*)(b2 + n0);
    float4 h0 = *(float4*)(h + row * FD + n0);
    float4 h1 = *(float4*)(h + (row + 1) * FD + n0);
    float4 o0, o1;
    o0.x = h0.x + silu_f(a00 + bb.x); o0.y = h0.y + silu_f(a01 + bb.y);
    o0.z = h0.z + silu_f(a02 + bb.z); o0.w = h0.w + silu_f(a03 + bb.w);
    o1.x = h1.x + silu_f(a10 + bb.x); o1.y = h1.y + silu_f(a11 + bb.y);
    o1.z = h1.z + silu_f(a12 + bb.z); o1.w = h1.w + silu_f(a13 + bb.w);
    *(float4*)(h + row * FD + n0) = o0;
    *(float4*)(h + (row + 1) * FD + n0) = o1;
    sH[(n0 + 0) * 18 + m0] = o0.x; sH[(n0 + 1) * 18 + m0] = o0.y;
    sH[(n0 + 2) * 18 + m0] = o0.z; sH[(n0 + 3) * 18 + m0] = o0.w;
    sH[(n0 + 0) * 18 + m0 + 1] = o1.x; sH[(n0 + 1) * 18 + m0 + 1] = o1.y;
    sH[(n0 + 2) * 18 + m0 + 1] = o1.z; sH[(n0 + 3) * 18 + m0 + 1] = o1.w;
    // phase 4: p,q epilogue (action layers)
    if (we_a != nullptr) {
        float4 wa = *(const float4*)(we_a + n0);
        float4 wp = *(const float4*)(we_p + n0);
        float p0 = o0.x * wa.x + o0.y * wa.y + o0.z * wa.z + o0.w * wa.w;
        float p1 = o1.x * wa.x + o1.y * wa.y + o1.z * wa.z + o1.w * wa.w;
        float q0 = o0.x * wp.x + o0.y * wp.y + o0.z * wp.z + o0.w * wp.w;
        float q1 = o1.x * wp.x + o1.y * wp.y + o1.z * wp.z + o1.w * wp.w;
#pragma unroll
        for (int off = 16; off > 0; off >>= 1) {
            p0 += __shfl_xor(p0, off); p1 += __shfl_xor(p1, off);
            q0 += __shfl_xor(q0, off); q1 += __shfl_xor(q1, off);
        }
        if (ng == 0) { p[row] = p0; p[row + 1] = p1; q[row] = q0; q[row + 1] = q1; }
    }
    // phase 5: next-layer W1 GEMM on h_new (row-local!)
    if (W1n != nullptr) {
        float c00 = 0, c01 = 0, c02 = 0, c03 = 0, c10 = 0, c11 = 0, c12 = 0, c13 = 0;
        for (int half = 0; half < 2; ++half) {
            __syncthreads();
            const float4* B4 = (const float4*)(W1n + half * 64 * FD);
            float4* Bs4 = (float4*)Bs;
#pragma unroll
            for (int i = 0; i < 8; ++i) Bs4[t + i * 256] = B4[t + i * 256];
            __syncthreads();
#pragma unroll 4
            for (int ff = 0; ff < 64; ++ff) {
                int f = half * 64 + ff;
                float2 av = *(const float2*)&sH[f * 18 + m0];
                float4 bv = *(const float4*)&Bs[ff * FD + n0];
                c00 += av.x * bv.x; c01 += av.x * bv.y; c02 += av.x * bv.z; c03 += av.x * bv.w;
                c10 += av.y * bv.x; c11 += av.y * bv.y; c12 += av.y * bv.z; c13 += av.y * bv.w;
            }
        }
        *(float4*)(hWout + row * FD + n0) = make_float4(c00, c01, c02, c03);
        *(float4*)(hWout + (row + 1) * FD + n0) = make_float4(c10, c11, c12, c13);
    }
}

// ---------------- per-atom action accumulation (inline vec/u): partials + x_cart ----------------
__global__ __launch_bounds__(256) void accum_kernel(
    const float* __restrict__ p, const float* __restrict__ q,
    const int* __restrict__ idxb, const float* __restrict__ x,
    const float* __restrict__ geo, int use_geo,
    const float* __restrict__ u0b,
    float* __restrict__ part, float* __restrict__ xcart)
{
    const int blk = blockIdx.x;
    const int t = threadIdx.x;
    const int w = t >> 6;
    const int lane = t & 63;
    const int a = blk * 4 + w;
    const int b = a >> 8;
    __shared__ float swe[4][KNN], swp[4][KNN];
    __shared__ float su[4][KNN][3], su0[4][KNN][3], sv[4][KNN][3];
    __shared__ float spart[4][18];
    if (lane < KNN) {
        int e = a * KNN + lane;
        int j = idxb[e];
        swe[w][lane] = tanhf(p[a] + p[j]);
        swp[w][lane] = tanhf(q[a] + q[j]);
        float f0 = x[j * 3 + 0] - x[a * 3 + 0]; f0 -= rintf(f0);
        float f1 = x[j * 3 + 1] - x[a * 3 + 1]; f1 -= rintf(f1);
        float f2 = x[j * 3 + 2] - x[a * 3 + 2]; f2 -= rintf(f2);
        float v0 = f0, v1 = f1, v2 = f2;
        if (use_geo) {
            const float* c = geo + b * 9;
            v0 = f0 * c[0] + f1 * c[3] + f2 * c[6];
            v1 = f0 * c[1] + f1 * c[4] + f2 * c[7];
            v2 = f0 * c[2] + f1 * c[5] + f2 * c[8];
        }
        float dd = sqrtf(v0 * v0 + v1 * v1 + v2 * v2);
        float inv = 1.f / (dd + 1e-12f);
        sv[w][lane][0] = v0; sv[w][lane][1] = v1; sv[w][lane][2] = v2;
        su[w][lane][0] = v0 * inv; su[w][lane][1] = v1 * inv; su[w][lane][2] = v2 * inv;
        su0[w][lane][0] = u0b[e * 3]; su0[w][lane][1] = u0b[e * 3 + 1]; su0[w][lane][2] = u0b[e * 3 + 2];
    }
    __syncthreads();
    float r[21];
#pragma unroll
    for (int i = 0; i < 21; ++i) r[i] = 0.f;
    if (lane < KNN) {
        float wgt = swe[w][lane];
        float ux = su[w][lane][0], uy = su[w][lane][1], uz = su[w][lane][2];
        r[0] = wgt * ux * ux; r[1] = wgt * ux * uy; r[2] = wgt * ux * uz;
        r[3] = wgt * uy * ux; r[4] = wgt * uy * uy; r[5] = wgt * uy * uz;
        r[6] = wgt * uz * ux; r[7] = wgt * uz * uy; r[8] = wgt * uz * uz;
        float wp = swp[w][lane];
        r[18] = wp * sv[w][lane][0]; r[19] = wp * sv[w][lane][1]; r[20] = wp * sv[w][lane][2];
    }
#pragma unroll
    for (int tt = 0; tt < 9; ++tt) {
        int pr = lane + (tt << 6);          // 0..575 = 24*24
        int j = pr / KNN, k = pr - j * KNN;
        float c0x = su0[w][j][1] * su0[w][k][2] - su0[w][j][2] * su0[w][k][1];
        float c0y = su0[w][j][2] * su0[w][k][0] - su0[w][j][0] * su0[w][k][2];
        float c0z = su0[w][j][0] * su0[w][k][1] - su0[w][j][1] * su0[w][k][0];
        float nn2 = c0x * c0x + c0y * c0y + c0z * c0z;
        if (nn2 > 1e-6f) {
            float cx = su[w][j][1] * su[w][k][2] - su[w][j][2] * su[w][k][1];
            float cy = su[w][j][2] * su[w][k][0] - su[w][j][0] * su[w][k][2];
            float cz = su[w][j][0] * su[w][k][1] - su[w][j][1] * su[w][k][0];
            float wt = swe[w][j] * swe[w][k];
            r[9]  += wt * cx * cx; r[10] += wt * cx * cy; r[11] += wt * cx * cz;
            r[12] += wt * cy * cx; r[13] += wt * cy * cy; r[14] += wt * cy * cz;
            r[15] += wt * cz * cx; r[16] += wt * cz * cy; r[17] += wt * cz * cz;
        }
    }
#pragma unroll
    for (int off = 32; off > 0; off >>= 1)
#pragma unroll
        for (int i = 0; i < 21; ++i) r[i] += __shfl_down(r[i], off);
    if (lane == 0) {
#pragma unroll
        for (int i = 0; i < 18; ++i) spart[w][i] = r[i];
        xcart[a * 3 + 0] = EPSA * r[18];
        xcart[a * 3 + 1] = EPSA * r[19];
        xcart[a * 3 + 2] = EPSA * r[20];
    }
    __syncthreads();
    if (t < 18)
        part[blk * 18 + t] = spart[0][t] + spart[1][t] + spart[2][t] + spart[3][t];
}

// ---------------- fused rho + pos: reduce partials, 3x3 chain, position/traj update ----------------
// grid 16 blocks (one per structure) x 256 threads.
__global__ __launch_bounds__(256) void rho_pos_kernel(const float* __restrict__ part,
    const float* __restrict__ xcart,
    float* __restrict__ rho, float* __restrict__ geo,
    float* __restrict__ x, float* __restrict__ traj,
    float* __restrict__ out, int first, int last)
{
    const int b = blockIdx.x;
    const int t = threadIdx.x;
    __shared__ float sIV[9];
    if (t < 64) {
        float r[18];
#pragma unroll
        for (int i = 0; i < 18; ++i) r[i] = part[(b * 64 + t) * 18 + i];
#pragma unroll
        for (int off = 32; off > 0; off >>= 1)
#pragma unroll
            for (int i = 0; i < 18; ++i) r[i] += __shfl_down(r[i], off);
        if (t == 0) {
            float A[9];
#pragma unroll
            for (int i = 0; i < 9; ++i) {
                float strain = r[i] / 6144.f;           // NAT*K
                float tri = r[9 + i] / 147456.f;        // NAT*K*K
                A[i] = ((i == 0 || i == 4 || i == 8) ? 1.f : 0.f) + EPSA * (strain + tri);
            }
            float N[9], IV[9];
            if (first) {
#pragma unroll
                for (int i = 0; i < 9; ++i) { N[i] = A[i]; IV[i] = (i == 0 || i == 4 || i == 8) ? 1.f : 0.f; }
            } else {
                float R[9], G[9];
#pragma unroll
                for (int i = 0; i < 9; ++i) { R[i] = rho[b * 9 + i]; G[i] = geo[b * 9 + i]; }
#pragma unroll
                for (int i = 0; i < 3; ++i)
#pragma unroll
                    for (int k = 0; k < 3; ++k)
                        N[i * 3 + k] = A[i * 3] * R[k] + A[i * 3 + 1] * R[3 + k] + A[i * 3 + 2] * R[6 + k];
                float det = G[0] * (G[4] * G[8] - G[5] * G[7])
                          - G[1] * (G[3] * G[8] - G[5] * G[6])
                          + G[2] * (G[3] * G[7] - G[4] * G[6]);
                float id = 1.f / det;
                IV[0] = (G[4] * G[8] - G[5] * G[7]) * id;
                IV[1] = (G[2] * G[7] - G[1] * G[8]) * id;
                IV[2] = (G[1] * G[5] - G[2] * G[4]) * id;
                IV[3] = (G[5] * G[6] - G[3] * G[8]) * id;
                IV[4] = (G[0] * G[8] - G[2] * G[6]) * id;
                IV[5] = (G[2] * G[3] - G[0] * G[5]) * id;
                IV[6] = (G[3] * G[7] - G[4] * G[6]) * id;
                IV[7] = (G[1] * G[6] - G[0] * G[7]) * id;
                IV[8] = (G[0] * G[4] - G[1] * G[3]) * id;
            }
#pragma unroll
            for (int i = 0; i < 9; ++i) {
                sIV[i] = IV[i];
                rho[b * 9 + i] = N[i];
                if (!last) geo[b * 9 + i] = N[i];
                else out[NATOMS * 3 + b * 9 + i] = N[i];
            }
        }
    }
    __syncthreads();
    for (int d = t; d < NATS * 3; d += 256) {
        int al = d / 3, dim = d - al * 3;
        int ga = b * NATS + al;
        int gi = ga * 3 + dim;
        float c0 = xcart[ga * 3 + 0], c1 = xcart[ga * 3 + 1], c2 = xcart[ga * 3 + 2];
        float tj = traj[gi] + xcart[gi];
        if (!last) {
            float xf = c0 * sIV[0 + dim] + c1 * sIV[3 + dim] + c2 * sIV[6 + dim];
            x[gi] += xf;
            traj[gi] = tj;
        } else {
            out[gi] = tj;
        }
    }
}

extern "C" void kernel_launch(void* const* d_in, const int* in_sizes, int n_in,
                              void* d_out, int out_size, void* d_ws, size_t ws_size,
                              hipStream_t stream)
{
    (void)in_sizes; (void)n_in; (void)out_size; (void)ws_size;
    const float* in_x = (const float*)d_in[1];
    const int*   z    = (const int*)d_in[2];
    const float* emb  = (const float*)d_in[4];
    const float* mW1  = (const float*)d_in[5];
    const float* mb1  = (const float*)d_in[6];
    const float* mW2  = (const float*)d_in[7];
    const float* mb2  = (const float*)d_in[8];
    const float* uW1  = (const float*)d_in[9];
    const float* ub1  = (const float*)d_in[10];
    const float* uW2  = (const float*)d_in[11];
    const float* ub2  = (const float*)d_in[12];
    const float* awe  = (const float*)d_in[13];
    const float* pwe  = (const float*)d_in[14];
    float* out = (float*)d_out;

    // workspace carve
    char* wsb = (char*)d_ws;
    size_t off = 0;
    auto carve = [&](size_t elems) {
        void* ptr = wsb + off;
        off += (elems * 4 + 255) & ~(size_t)255;
        return ptr;
    };
    float* traj  = (float*)carve(NATOMS * 3);
    float* part  = (float*)carve(1024 * 18);
    float* x     = (float*)carve(NATOMS * 3);
    float* xcart = (float*)carve(NATOMS * 3);
    float* p     = (float*)carve(NATOMS);
    float* q     = (float*)carve(NATOMS);
    float* rho   = (float*)carve(NB * 9);
    float* geo   = (float*)carve(NB * 9);
    float* u0    = (float*)carve(NEDGE * 3);
    float* h     = (float*)carve(NATOMS * FD);
    float* hWa   = (float*)carve(NATOMS * FD);
    float* hWb   = (float*)carve(NATOMS * FD);
    int*   idx   = (int*)carve(NEDGE);

    init_kernel<<<2048, 256, 0, stream>>>(in_x, z, emb, x, h, traj);
    knn_kernel<<<NATOMS, 64, 0, stream>>>(x, idx, u0);
    gemm1_kernel<<<256, 256, 0, stream>>>(h, mW1, hWa);    // hW for mpnn layer 0

    // ping-pong hW buffers across the 8 fused layers
    float* hw_in = hWa;
    float* hw_out = hWb;

    // message-passing layers (identity geometry throughout)
    for (int l = 0; l < 4; ++l) {
        const float* W1n = (l < 3) ? (mW1 + (l + 1) * 129 * 128) : uW1;  // next layer's W1
        layer_kernel<<<256, 256, 0, stream>>>(hw_in, idx, x, geo, 0,
            mW1 + l * 129 * 128 + 128 * 128, mb1 + l * 128,
            mW2 + l * 128 * 128, mb2 + l * 128,
            W1n, hw_out, h,
            nullptr, nullptr, nullptr, nullptr);
        float* tmp = hw_in; hw_in = hw_out; hw_out = tmp;
    }
    // action layers
    for (int l = 0; l < 4; ++l) {
        const float* W1n = (l < 3) ? (uW1 + (l + 1) * 129 * 128) : nullptr;
        layer_kernel<<<256, 256, 0, stream>>>(hw_in, idx, x, geo, (l > 0) ? 1 : 0,
            uW1 + l * 129 * 128 + 128 * 128, ub1 + l * 128,
            uW2 + l * 128 * 128, ub2 + l * 128,
            W1n, hw_out, h,
            awe + l * 128, pwe + l * 128, p, q);
        float* tmp = hw_in; hw_in = hw_out; hw_out = tmp;
        accum_kernel<<<1024, 256, 0, stream>>>(p, q, idx, x, geo, (l > 0) ? 1 : 0,
            u0, part, xcart);
        rho_pos_kernel<<<NB, 256, 0, stream>>>(part, xcart, rho, geo, x, traj, out,
            (l == 0) ? 1 : 0, (l == 3) ? 1 : 0);
    }
}

// Round 4
// 347.516 us; speedup vs baseline: 2.9850x; 1.2650x over previous
//
#include <hip/hip_runtime.h>

// Problem constants (reference: B=16, NAT=256, K=24, F=128, L=4, EPS=0.01)
#define NB 16
#define NATS 256
#define KNN 24
#define FD 128
#define EPSA 0.01f
#define NATOMS (NB * NATS)      // 4096
#define NEDGE (NATOMS * KNN)    // 98304

__device__ __forceinline__ float silu_f(float v) { return v / (1.f + __expf(-v)); }

// ---------------- fused init + layer-0 W1 GEMM ----------------
// grid 256 blocks x 256 threads; block = 16 atoms. Writes x, traj, h, hW0.
__global__ __launch_bounds__(256) void init_gemm1_kernel(
    const float* __restrict__ xin, const int* __restrict__ z,
    const float* __restrict__ emb, const float* __restrict__ W1,
    float* __restrict__ x, float* __restrict__ traj,
    float* __restrict__ h, float* __restrict__ hW)
{
    __shared__ float As[128 * 18];    // h^T [f][m]
    __shared__ float Bs[128 * 128];   // full W1
    const int t = threadIdx.x;
    const int atom0 = blockIdx.x * 16;
    if (t < 48) {
        int gi = atom0 * 3 + t;
        float v = xin[gi];
        x[gi] = v - floorf(v);
        traj[gi] = 0.f;
    }
    {
        const int r = t >> 4;
        const int f0 = (t & 15) * 8;
        const int a = atom0 + r;
        const float4* src = (const float4*)(emb + z[a] * FD + f0);
        float4 v0 = src[0], v1 = src[1];
        float4* dst = (float4*)(h + a * FD + f0);
        dst[0] = v0; dst[1] = v1;
        As[(f0 + 0) * 18 + r] = v0.x; As[(f0 + 1) * 18 + r] = v0.y;
        As[(f0 + 2) * 18 + r] = v0.z; As[(f0 + 3) * 18 + r] = v0.w;
        As[(f0 + 4) * 18 + r] = v1.x; As[(f0 + 5) * 18 + r] = v1.y;
        As[(f0 + 6) * 18 + r] = v1.z; As[(f0 + 7) * 18 + r] = v1.w;
    }
    {
        const float4* B4 = (const float4*)W1;
        float4* Bs4 = (float4*)Bs;
#pragma unroll
        for (int i = 0; i < 16; ++i) Bs4[t + i * 256] = B4[t + i * 256];
    }
    __syncthreads();
    const int ng = t & 31, mg = t >> 5;
    const int n0 = ng * 4, m0 = mg * 2;
    float a00 = 0, a01 = 0, a02 = 0, a03 = 0, a10 = 0, a11 = 0, a12 = 0, a13 = 0;
#pragma unroll 8
    for (int f = 0; f < 128; ++f) {
        float2 av = *(const float2*)&As[f * 18 + m0];
        float4 bv = *(const float4*)&Bs[f * FD + n0];
        a00 += av.x * bv.x; a01 += av.x * bv.y; a02 += av.x * bv.z; a03 += av.x * bv.w;
        a10 += av.y * bv.x; a11 += av.y * bv.y; a12 += av.y * bv.z; a13 += av.y * bv.w;
    }
    int row = atom0 + m0;
    *(float4*)(hW + row * FD + n0) = make_float4(a00, a01, a02, a03);
    *(float4*)(hW + (row + 1) * FD + n0) = make_float4(a10, a11, a12, a13);
}

// ---------------- kNN: per-atom wave, iterative argmin (matches top_k tie-break) ----------------
// Epilogue: lanes 0..23 write u0 (unit edge vectors, identity cell) and dist0.
__global__ __launch_bounds__(64) void knn_kernel(const float* __restrict__ x,
    int* __restrict__ idxb, float* __restrict__ u0, float* __restrict__ dist0)
{
    const int a = blockIdx.x;          // global atom
    const int b = a >> 8;
    const int lane = threadIdx.x;
    const float xi0 = x[a * 3 + 0], xi1 = x[a * 3 + 1], xi2 = x[a * 3 + 2];
    unsigned long long key[4];
#pragma unroll
    for (int tt = 0; tt < 4; ++tt) {
        int jg = b * NATS + lane + tt * 64;
        float d0 = x[jg * 3 + 0] - xi0; d0 -= rintf(d0);
        float d1 = x[jg * 3 + 1] - xi1; d1 -= rintf(d1);
        float d2 = x[jg * 3 + 2] - xi2; d2 -= rintf(d2);
        float dd = sqrtf(d0 * d0 + d1 * d1 + d2 * d2);
        if (jg == a) dd += 1e6f;       // exclude self (ref adds 1e6*eye)
        key[tt] = ((unsigned long long)__float_as_uint(dd) << 32) | (unsigned)jg;
    }
    int myj = 0;
    for (int sel = 0; sel < KNN; ++sel) {
        unsigned long long m = key[0];
        if (key[1] < m) m = key[1];
        if (key[2] < m) m = key[2];
        if (key[3] < m) m = key[3];
#pragma unroll
        for (int off = 32; off > 0; off >>= 1) {
            unsigned lo = (unsigned)__shfl_xor((int)(unsigned)(m & 0xffffffffu), off);
            unsigned hi = (unsigned)__shfl_xor((int)(unsigned)(m >> 32), off);
            unsigned long long o = ((unsigned long long)hi << 32) | lo;
            if (o < m) m = o;
        }
        int jw = (int)(m & 0xffffffffu);
        if (lane == 0) idxb[a * KNN + sel] = jw;
        if (lane == sel) myj = jw;
#pragma unroll
        for (int tt = 0; tt < 4; ++tt) if (key[tt] == m) key[tt] = ~0ull;
    }
    if (lane < KNN) {
        float f0 = x[myj * 3 + 0] - xi0; f0 -= rintf(f0);
        float f1 = x[myj * 3 + 1] - xi1; f1 -= rintf(f1);
        float f2 = x[myj * 3 + 2] - xi2; f2 -= rintf(f2);
        float dd = sqrtf(f0 * f0 + f1 * f1 + f2 * f2);
        float inv = 1.f / (dd + 1e-12f);
        int e = a * KNN + lane;
        u0[e * 3 + 0] = f0 * inv; u0[e * 3 + 1] = f1 * inv; u0[e * 3 + 2] = f2 * inv;
        dist0[e] = dd;
    }
}

// ---------------- fused layer: dist + agg + W2 GEMM + residual (+pq) + next W1 GEMM ----------------
// grid 512 blocks x 256 threads; block = 8 atoms; 2 blocks/CU.
__global__ __launch_bounds__(256, 2) void layer_kernel(
    const float* __restrict__ hW, const int* __restrict__ idxb,
    const float* __restrict__ dist0,                  // non-null => use precomputed dist
    const float* __restrict__ x, const float* __restrict__ geo, int use_geo,
    const float* __restrict__ wl, const float* __restrict__ b1,
    const float* __restrict__ W2, const float* __restrict__ b2,
    const float* __restrict__ W1n, float* __restrict__ hWout,
    float* __restrict__ h,
    const float* __restrict__ we_a, const float* __restrict__ we_p,
    float* __restrict__ p, float* __restrict__ q)
{
    __shared__ float As[128 * 9];     // agg output transposed [g][a], odd stride
    __shared__ float sH[128 * 9];     // h_new transposed [g][a]
    __shared__ float Bs[128 * 128];   // full weight matrix
    __shared__ int   sIdx[8 * KNN];
    __shared__ float sDist[8 * KNN];
    const int t = threadIdx.x;
    const int atom0 = blockIdx.x * 8;
    // phase 1: indices + distances
    if (t < 8 * KNN) {
        int a = atom0 + (t / KNN);
        int j = idxb[atom0 * KNN + t];
        sIdx[t] = j;
        float d;
        if (dist0 != nullptr) {
            d = dist0[atom0 * KNN + t];
        } else {
            float f0 = x[j * 3 + 0] - x[a * 3 + 0]; f0 -= rintf(f0);
            float f1 = x[j * 3 + 1] - x[a * 3 + 1]; f1 -= rintf(f1);
            float f2 = x[j * 3 + 2] - x[a * 3 + 2]; f2 -= rintf(f2);
            float v0 = f0, v1 = f1, v2 = f2;
            if (use_geo) {
                const float* c = geo + (a >> 8) * 9;
                v0 = f0 * c[0] + f1 * c[3] + f2 * c[6];
                v1 = f0 * c[1] + f1 * c[4] + f2 * c[7];
                v2 = f0 * c[2] + f1 * c[5] + f2 * c[8];
            }
            d = sqrtf(v0 * v0 + v1 * v1 + v2 * v2);
        }
        sDist[t] = d;
    }
    __syncthreads();
    // phase 2: agg s_a[g] = sum_k silu(hW[j][g] + d*wl[g] + b1[g])
    {
        const int g = t & 127;
        const int sub = t >> 7;       // 0..1
        const float wlg = wl[g];
        const float b1g = b1[g];
#pragma unroll
        for (int rep = 0; rep < 4; ++rep) {
            const int a = rep * 2 + sub;
            float s = 0.f;
#pragma unroll 8
            for (int k = 0; k < KNN; ++k) {
                int j = sIdx[a * KNN + k];
                float v = hW[j * FD + g] + sDist[a * KNN + k] * wlg + b1g;
                s += silu_f(v);
            }
            As[g * 9 + a] = s;
        }
    }
    // stage full W2 (Bs untouched so far; no barrier needed before)
    {
        const float4* B4 = (const float4*)W2;
        float4* Bs4 = (float4*)Bs;
#pragma unroll
        for (int i = 0; i < 16; ++i) Bs4[t + i * 256] = B4[t + i * 256];
    }
    __syncthreads();
    // phase 3: W2 GEMM (each thread: 1 row x 4 cols), residual, h write
    const int ng = t & 31, mg = t >> 5;   // mg 0..7
    const int n0 = ng * 4;
    float c0 = 0, c1 = 0, c2 = 0, c3 = 0;
#pragma unroll 8
    for (int f = 0; f < 128; ++f) {
        float av = As[f * 9 + mg];
        float4 bv = *(const float4*)&Bs[f * FD + n0];
        c0 += av * bv.x; c1 += av * bv.y; c2 += av * bv.z; c3 += av * bv.w;
    }
    const int row = atom0 + mg;
    float4 bb = *(const float4*)(b2 + n0);
    float4 h0 = *(float4*)(h + row * FD + n0);
    float4 o0;
    o0.x = h0.x + silu_f(c0 + bb.x); o0.y = h0.y + silu_f(c1 + bb.y);
    o0.z = h0.z + silu_f(c2 + bb.z); o0.w = h0.w + silu_f(c3 + bb.w);
    *(float4*)(h + row * FD + n0) = o0;
    sH[(n0 + 0) * 9 + mg] = o0.x; sH[(n0 + 1) * 9 + mg] = o0.y;
    sH[(n0 + 2) * 9 + mg] = o0.z; sH[(n0 + 3) * 9 + mg] = o0.w;
    // phase 4: p,q epilogue (action layers)
    if (we_a != nullptr) {
        float4 wa = *(const float4*)(we_a + n0);
        float4 wp = *(const float4*)(we_p + n0);
        float p0 = o0.x * wa.x + o0.y * wa.y + o0.z * wa.z + o0.w * wa.w;
        float q0 = o0.x * wp.x + o0.y * wp.y + o0.z * wp.z + o0.w * wp.w;
#pragma unroll
        for (int off = 16; off > 0; off >>= 1) {
            p0 += __shfl_xor(p0, off); q0 += __shfl_xor(q0, off);
        }
        if (ng == 0) { p[row] = p0; q[row] = q0; }
    }
    // phase 5: next-layer W1 GEMM on h_new (row-local)
    if (W1n != nullptr) {
        __syncthreads();              // everyone done reading Bs(W2)
        {
            const float4* B4 = (const float4*)W1n;
            float4* Bs4 = (float4*)Bs;
#pragma unroll
            for (int i = 0; i < 16; ++i) Bs4[t + i * 256] = B4[t + i * 256];
        }
        __syncthreads();
        float d0 = 0, d1 = 0, d2 = 0, d3 = 0;
#pragma unroll 8
        for (int f = 0; f < 128; ++f) {
            float av = sH[f * 9 + mg];
            float4 bv = *(const float4*)&Bs[f * FD + n0];
            d0 += av * bv.x; d1 += av * bv.y; d2 += av * bv.z; d3 += av * bv.w;
        }
        *(float4*)(hWout + row * FD + n0) = make_float4(d0, d1, d2, d3);
    }
}

// ---------------- per-atom action accumulation (inline vec/u): partials + x_cart ----------------
__global__ __launch_bounds__(256) void accum_kernel(
    const float* __restrict__ p, const float* __restrict__ q,
    const int* __restrict__ idxb, const float* __restrict__ x,
    const float* __restrict__ geo, int use_geo,
    const float* __restrict__ u0b,
    float* __restrict__ part, float* __restrict__ xcart)
{
    const int blk = blockIdx.x;
    const int t = threadIdx.x;
    const int w = t >> 6;
    const int lane = t & 63;
    const int a = blk * 4 + w;
    const int b = a >> 8;
    __shared__ float swe[4][KNN], swp[4][KNN];
    __shared__ float su[4][KNN][3], su0[4][KNN][3], sv[4][KNN][3];
    __shared__ float spart[4][18];
    if (lane < KNN) {
        int e = a * KNN + lane;
        int j = idxb[e];
        swe[w][lane] = tanhf(p[a] + p[j]);
        swp[w][lane] = tanhf(q[a] + q[j]);
        float f0 = x[j * 3 + 0] - x[a * 3 + 0]; f0 -= rintf(f0);
        float f1 = x[j * 3 + 1] - x[a * 3 + 1]; f1 -= rintf(f1);
        float f2 = x[j * 3 + 2] - x[a * 3 + 2]; f2 -= rintf(f2);
        float v0 = f0, v1 = f1, v2 = f2;
        if (use_geo) {
            const float* c = geo + b * 9;
            v0 = f0 * c[0] + f1 * c[3] + f2 * c[6];
            v1 = f0 * c[1] + f1 * c[4] + f2 * c[7];
            v2 = f0 * c[2] + f1 * c[5] + f2 * c[8];
        }
        float dd = sqrtf(v0 * v0 + v1 * v1 + v2 * v2);
        float inv = 1.f / (dd + 1e-12f);
        sv[w][lane][0] = v0; sv[w][lane][1] = v1; sv[w][lane][2] = v2;
        su[w][lane][0] = v0 * inv; su[w][lane][1] = v1 * inv; su[w][lane][2] = v2 * inv;
        su0[w][lane][0] = u0b[e * 3]; su0[w][lane][1] = u0b[e * 3 + 1]; su0[w][lane][2] = u0b[e * 3 + 2];
    }
    __syncthreads();
    float r[21];
#pragma unroll
    for (int i = 0; i < 21; ++i) r[i] = 0.f;
    if (lane < KNN) {
        float wgt = swe[w][lane];
        float ux = su[w][lane][0], uy = su[w][lane][1], uz = su[w][lane][2];
        r[0] = wgt * ux * ux; r[1] = wgt * ux * uy; r[2] = wgt * ux * uz;
        r[3] = wgt * uy * ux; r[4] = wgt * uy * uy; r[5] = wgt * uy * uz;
        r[6] = wgt * uz * ux; r[7] = wgt * uz * uy; r[8] = wgt * uz * uz;
        float wp = swp[w][lane];
        r[18] = wp * sv[w][lane][0]; r[19] = wp * sv[w][lane][1]; r[20] = wp * sv[w][lane][2];
    }
#pragma unroll
    for (int tt = 0; tt < 9; ++tt) {
        int pr = lane + (tt << 6);          // 0..575 = 24*24
        int j = pr / KNN, k = pr - j * KNN;
        float c0x = su0[w][j][1] * su0[w][k][2] - su0[w][j][2] * su0[w][k][1];
        float c0y = su0[w][j][2] * su0[w][k][0] - su0[w][j][0] * su0[w][k][2];
        float c0z = su0[w][j][0] * su0[w][k][1] - su0[w][j][1] * su0[w][k][0];
        float nn2 = c0x * c0x + c0y * c0y + c0z * c0z;
        if (nn2 > 1e-6f) {
            float cx = su[w][j][1] * su[w][k][2] - su[w][j][2] * su[w][k][1];
            float cy = su[w][j][2] * su[w][k][0] - su[w][j][0] * su[w][k][2];
            float cz = su[w][j][0] * su[w][k][1] - su[w][j][1] * su[w][k][0];
            float wt = swe[w][j] * swe[w][k];
            r[9]  += wt * cx * cx; r[10] += wt * cx * cy; r[11] += wt * cx * cz;
            r[12] += wt * cy * cx; r[13] += wt * cy * cy; r[14] += wt * cy * cz;
            r[15] += wt * cz * cx; r[16] += wt * cz * cy; r[17] += wt * cz * cz;
        }
    }
#pragma unroll
    for (int off = 32; off > 0; off >>= 1)
#pragma unroll
        for (int i = 0; i < 21; ++i) r[i] += __shfl_down(r[i], off);
    if (lane == 0) {
#pragma unroll
        for (int i = 0; i < 18; ++i) spart[w][i] = r[i];
        xcart[a * 3 + 0] = EPSA * r[18];
        xcart[a * 3 + 1] = EPSA * r[19];
        xcart[a * 3 + 2] = EPSA * r[20];
    }
    __syncthreads();
    if (t < 18)
        part[blk * 18 + t] = spart[0][t] + spart[1][t] + spart[2][t] + spart[3][t];
}

// ---------------- fused rho + pos: reduce partials, 3x3 chain, position/traj update ----------------
// grid 16 blocks (one per structure) x 256 threads.
__global__ __launch_bounds__(256) void rho_pos_kernel(const float* __restrict__ part,
    const float* __restrict__ xcart,
    float* __restrict__ rho, float* __restrict__ geo,
    float* __restrict__ x, float* __restrict__ traj,
    float* __restrict__ out, int first, int last)
{
    const int b = blockIdx.x;
    const int t = threadIdx.x;
    __shared__ float sIV[9];
    if (t < 64) {
        float r[18];
#pragma unroll
        for (int i = 0; i < 18; ++i) r[i] = part[(b * 64 + t) * 18 + i];
#pragma unroll
        for (int off = 32; off > 0; off >>= 1)
#pragma unroll
            for (int i = 0; i < 18; ++i) r[i] += __shfl_down(r[i], off);
        if (t == 0) {
            float A[9];
#pragma unroll
            for (int i = 0; i < 9; ++i) {
                float strain = r[i] / 6144.f;           // NAT*K
                float tri = r[9 + i] / 147456.f;        // NAT*K*K
                A[i] = ((i == 0 || i == 4 || i == 8) ? 1.f : 0.f) + EPSA * (strain + tri);
            }
            float N[9], IV[9];
            if (first) {
#pragma unroll
                for (int i = 0; i < 9; ++i) { N[i] = A[i]; IV[i] = (i == 0 || i == 4 || i == 8) ? 1.f : 0.f; }
            } else {
                float R[9], G[9];
#pragma unroll
                for (int i = 0; i < 9; ++i) { R[i] = rho[b * 9 + i]; G[i] = geo[b * 9 + i]; }
#pragma unroll
                for (int i = 0; i < 3; ++i)
#pragma unroll
                    for (int k = 0; k < 3; ++k)
                        N[i * 3 + k] = A[i * 3] * R[k] + A[i * 3 + 1] * R[3 + k] + A[i * 3 + 2] * R[6 + k];
                float det = G[0] * (G[4] * G[8] - G[5] * G[7])
                          - G[1] * (G[3] * G[8] - G[5] * G[6])
                          + G[2] * (G[3] * G[7] - G[4] * G[6]);
                float id = 1.f / det;
                IV[0] = (G[4] * G[8] - G[5] * G[7]) * id;
                IV[1] = (G[2] * G[7] - G[1] * G[8]) * id;
                IV[2] = (G[1] * G[5] - G[2] * G[4]) * id;
                IV[3] = (G[5] * G[6] - G[3] * G[8]) * id;
                IV[4] = (G[0] * G[8] - G[2] * G[6]) * id;
                IV[5] = (G[2] * G[3] - G[0] * G[5]) * id;
                IV[6] = (G[3] * G[7] - G[4] * G[6]) * id;
                IV[7] = (G[1] * G[6] - G[0] * G[7]) * id;
                IV[8] = (G[0] * G[4] - G[1] * G[3]) * id;
            }
#pragma unroll
            for (int i = 0; i < 9; ++i) {
                sIV[i] = IV[i];
                rho[b * 9 + i] = N[i];
                if (!last) geo[b * 9 + i] = N[i];
                else out[NATOMS * 3 + b * 9 + i] = N[i];
            }
        }
    }
    __syncthreads();
    for (int d = t; d < NATS * 3; d += 256) {
        int al = d / 3, dim = d - al * 3;
        int ga = b * NATS + al;
        int gi = ga * 3 + dim;
        float c0 = xcart[ga * 3 + 0], c1 = xcart[ga * 3 + 1], c2 = xcart[ga * 3 + 2];
        float tj = traj[gi] + xcart[gi];
        if (!last) {
            float xf = c0 * sIV[0 + dim] + c1 * sIV[3 + dim] + c2 * sIV[6 + dim];
            x[gi] += xf;
            traj[gi] = tj;
        } else {
            out[gi] = tj;
        }
    }
}

extern "C" void kernel_launch(void* const* d_in, const int* in_sizes, int n_in,
                              void* d_out, int out_size, void* d_ws, size_t ws_size,
                              hipStream_t stream)
{
    (void)in_sizes; (void)n_in; (void)out_size; (void)ws_size;
    const float* in_x = (const float*)d_in[1];
    const int*   z    = (const int*)d_in[2];
    const float* emb  = (const float*)d_in[4];
    const float* mW1  = (const float*)d_in[5];
    const float* mb1  = (const float*)d_in[6];
    const float* mW2  = (const float*)d_in[7];
    const float* mb2  = (const float*)d_in[8];
    const float* uW1  = (const float*)d_in[9];
    const float* ub1  = (const float*)d_in[10];
    const float* uW2  = (const float*)d_in[11];
    const float* ub2  = (const float*)d_in[12];
    const float* awe  = (const float*)d_in[13];
    const float* pwe  = (const float*)d_in[14];
    float* out = (float*)d_out;

    // workspace carve
    char* wsb = (char*)d_ws;
    size_t off = 0;
    auto carve = [&](size_t elems) {
        void* ptr = wsb + off;
        off += (elems * 4 + 255) & ~(size_t)255;
        return ptr;
    };
    float* traj  = (float*)carve(NATOMS * 3);
    float* part  = (float*)carve(1024 * 18);
    float* x     = (float*)carve(NATOMS * 3);
    float* xcart = (float*)carve(NATOMS * 3);
    float* p     = (float*)carve(NATOMS);
    float* q     = (float*)carve(NATOMS);
    float* rho   = (float*)carve(NB * 9);
    float* geo   = (float*)carve(NB * 9);
    float* u0    = (float*)carve(NEDGE * 3);
    float* dist0 = (float*)carve(NEDGE);
    float* h     = (float*)carve(NATOMS * FD);
    float* hWa   = (float*)carve(NATOMS * FD);
    float* hWb   = (float*)carve(NATOMS * FD);
    int*   idx   = (int*)carve(NEDGE);

    init_gemm1_kernel<<<256, 256, 0, stream>>>(in_x, z, emb, mW1, x, traj, h, hWa);
    knn_kernel<<<NATOMS, 64, 0, stream>>>(x, idx, u0, dist0);

    float* hw_in = hWa;
    float* hw_out = hWb;

    // message-passing layers (identity geometry, x fixed -> dist0 reuse)
    for (int l = 0; l < 4; ++l) {
        const float* W1n = (l < 3) ? (mW1 + (l + 1) * 129 * 128) : uW1;
        layer_kernel<<<512, 256, 0, stream>>>(hw_in, idx, dist0, x, geo, 0,
            mW1 + l * 129 * 128 + 128 * 128, mb1 + l * 128,
            mW2 + l * 128 * 128, mb2 + l * 128,
            W1n, hw_out, h,
            nullptr, nullptr, nullptr, nullptr);
        float* tmp = hw_in; hw_in = hw_out; hw_out = tmp;
    }
    // action layers
    for (int l = 0; l < 4; ++l) {
        const float* W1n = (l < 3) ? (uW1 + (l + 1) * 129 * 128) : nullptr;
        const float* d0 = (l == 0) ? dist0 : nullptr;   // layer 0: identity geo, x unchanged
        layer_kernel<<<512, 256, 0, stream>>>(hw_in, idx, d0, x, geo, (l > 0) ? 1 : 0,
            uW1 + l * 129 * 128 + 128 * 128, ub1 + l * 128,
            uW2 + l * 128 * 128, ub2 + l * 128,
            W1n, hw_out, h,
            awe + l * 128, pwe + l * 128, p, q);
        float* tmp = hw_in; hw_in = hw_out; hw_out = tmp;
        accum_kernel<<<1024, 256, 0, stream>>>(p, q, idx, x, geo, (l > 0) ? 1 : 0,
            u0, part, xcart);
        rho_pos_kernel<<<NB, 256, 0, stream>>>(part, xcart, rho, geo, x, traj, out,
            (l == 0) ? 1 : 0, (l == 3) ? 1 : 0);
    }
}

// Round 6
// 339.119 us; speedup vs baseline: 3.0590x; 1.0248x over previous
//
#include <hip/hip_runtime.h>

// Problem constants (reference: B=16, NAT=256, K=24, F=128, L=4, EPS=0.01)
#define NB 16
#define NATS 256
#define KNN 24
#define FD 128
#define EPSA 0.01f
#define NATOMS (NB * NATS)      // 4096
#define NEDGE (NATOMS * KNN)    // 98304

typedef __attribute__((ext_vector_type(8))) short short8;   // 8 bf16 (a/b frag)
typedef __attribute__((ext_vector_type(4))) float f32x4;    // C/D frag

__device__ __forceinline__ float silu_f(float v) { return v / (1.f + __expf(-v)); }

__device__ __forceinline__ short f2b(float f) {             // fp32 -> bf16 (RNE)
    union { float f; unsigned u; } v; v.f = f;
    unsigned r = v.u + 0x7FFFu + ((v.u >> 16) & 1u);
    return (short)(r >> 16);
}
__device__ __forceinline__ float b2f(short s) {
    return __uint_as_float(((unsigned)(unsigned short)s) << 16);
}
// b-frag: 16B contiguous chunk of transposed weight [n][k]
__device__ __forceinline__ short8 ldb(const short* __restrict__ W, int n, int ks, int quad) {
    return *(const short8*)&W[n * 128 + ks * 32 + quad * 8];
}

// ---------------- prep: transpose + bf16 hi/lo split of all 16 weight matrices ----------------
// m = {mW1 l0..3, mW2 l0..3, uW1 l0..3, uW2 l0..3}; layout [n][k] bf16
__global__ __launch_bounds__(256) void prep_kernel(
    const float* __restrict__ mW1, const float* __restrict__ mW2,
    const float* __restrict__ uW1, const float* __restrict__ uW2,
    short* __restrict__ wh, short* __restrict__ wl_)
{
    int tid = blockIdx.x * 256 + threadIdx.x;   // 1024*256 = 262144 = 16*16384
    int m = tid >> 14;
    int e = tid & 16383;
    int n = e >> 7, k = e & 127;
    const float* src;
    int l = m & 3;
    switch (m >> 2) {
        case 0:  src = mW1 + l * 129 * 128; break;
        case 1:  src = mW2 + l * 128 * 128; break;
        case 2:  src = uW1 + l * 129 * 128; break;
        default: src = uW2 + l * 128 * 128; break;
    }
    float w = src[k * 128 + n];
    short hi = f2b(w);
    wh[tid] = hi;
    wl_[tid] = f2b(w - b2f(hi));
}

// ---------------- fused init + layer-0 W1 split-MFMA GEMM ----------------
// grid 256 x 256; block = 16 atoms. Writes x, traj, h, hW0.
__global__ __launch_bounds__(256) void init_kernel(
    const float* __restrict__ xin, const int* __restrict__ z,
    const float* __restrict__ emb,
    const short* __restrict__ W1h, const short* __restrict__ W1l,
    float* __restrict__ x, float* __restrict__ traj,
    float* __restrict__ h, float* __restrict__ hW)
{
    __shared__ short sAH[16 * 136];   // h bf16 hi [m][k]
    __shared__ short sAL[16 * 136];   // h bf16 lo
    const int t = threadIdx.x;
    const int atom0 = blockIdx.x * 16;
    if (t < 48) {
        int gi = atom0 * 3 + t;
        float v = xin[gi];
        x[gi] = v - floorf(v);
        traj[gi] = 0.f;
    }
    {
        const int r = t >> 4;
        const int f0 = (t & 15) * 8;
        const int a = atom0 + r;
        const float4* src = (const float4*)(emb + z[a] * FD + f0);
        float4 v0 = src[0], v1 = src[1];
        float4* dst = (float4*)(h + a * FD + f0);
        dst[0] = v0; dst[1] = v1;
        float vv[8] = {v0.x, v0.y, v0.z, v0.w, v1.x, v1.y, v1.z, v1.w};
        short8 shv, slv;
#pragma unroll
        for (int i = 0; i < 8; ++i) {
            short hi = f2b(vv[i]);
            shv[i] = hi; slv[i] = f2b(vv[i] - b2f(hi));
        }
        *(short8*)&sAH[r * 136 + f0] = shv;
        *(short8*)&sAL[r * 136 + f0] = slv;
    }
    __syncthreads();
    const int w = t >> 6, lane = t & 63, quad = lane >> 4, col = lane & 15;
    const int n0 = w * 32;
    f32x4 acc0 = {0.f, 0.f, 0.f, 0.f}, acc1 = {0.f, 0.f, 0.f, 0.f};
#pragma unroll
    for (int ks = 0; ks < 4; ++ks) {
        short8 ah = *(const short8*)&sAH[col * 136 + ks * 32 + quad * 8];
        short8 al = *(const short8*)&sAL[col * 136 + ks * 32 + quad * 8];
        short8 bh0 = ldb(W1h, n0 + col, ks, quad);
        short8 bl0 = ldb(W1l, n0 + col, ks, quad);
        short8 bh1 = ldb(W1h, n0 + 16 + col, ks, quad);
        short8 bl1 = ldb(W1l, n0 + 16 + col, ks, quad);
        acc0 = __builtin_amdgcn_mfma_f32_16x16x32_bf16(ah, bh0, acc0, 0, 0, 0);
        acc0 = __builtin_amdgcn_mfma_f32_16x16x32_bf16(ah, bl0, acc0, 0, 0, 0);
        acc0 = __builtin_amdgcn_mfma_f32_16x16x32_bf16(al, bh0, acc0, 0, 0, 0);
        acc1 = __builtin_amdgcn_mfma_f32_16x16x32_bf16(ah, bh1, acc1, 0, 0, 0);
        acc1 = __builtin_amdgcn_mfma_f32_16x16x32_bf16(ah, bl1, acc1, 0, 0, 0);
        acc1 = __builtin_amdgcn_mfma_f32_16x16x32_bf16(al, bh1, acc1, 0, 0, 0);
    }
#pragma unroll
    for (int nt = 0; nt < 2; ++nt) {
        int gn = n0 + nt * 16 + col;
        f32x4 av = (nt == 0) ? acc0 : acc1;
#pragma unroll
        for (int r = 0; r < 4; ++r) {
            int row = quad * 4 + r;
            hW[(atom0 + row) * FD + gn] = av[r];
        }
    }
}

// ---------------- kNN: per-atom wave, iterative argmin (matches top_k tie-break) ----------------
__global__ __launch_bounds__(64) void knn_kernel(const float* __restrict__ x,
    int* __restrict__ idxb, float* __restrict__ u0, float* __restrict__ dist0)
{
    const int a = blockIdx.x;
    const int b = a >> 8;
    const int lane = threadIdx.x;
    const float xi0 = x[a * 3 + 0], xi1 = x[a * 3 + 1], xi2 = x[a * 3 + 2];
    unsigned long long key[4];
#pragma unroll
    for (int tt = 0; tt < 4; ++tt) {
        int jg = b * NATS + lane + tt * 64;
        float d0 = x[jg * 3 + 0] - xi0; d0 -= rintf(d0);
        float d1 = x[jg * 3 + 1] - xi1; d1 -= rintf(d1);
        float d2 = x[jg * 3 + 2] - xi2; d2 -= rintf(d2);
        float dd = sqrtf(d0 * d0 + d1 * d1 + d2 * d2);
        if (jg == a) dd += 1e6f;
        key[tt] = ((unsigned long long)__float_as_uint(dd) << 32) | (unsigned)jg;
    }
    int myj = 0;
    for (int sel = 0; sel < KNN; ++sel) {
        unsigned long long m = key[0];
        if (key[1] < m) m = key[1];
        if (key[2] < m) m = key[2];
        if (key[3] < m) m = key[3];
#pragma unroll
        for (int off = 32; off > 0; off >>= 1) {
            unsigned lo = (unsigned)__shfl_xor((int)(unsigned)(m & 0xffffffffu), off);
            unsigned hi = (unsigned)__shfl_xor((int)(unsigned)(m >> 32), off);
            unsigned long long o = ((unsigned long long)hi << 32) | lo;
            if (o < m) m = o;
        }
        int jw = (int)(m & 0xffffffffu);
        if (lane == 0) idxb[a * KNN + sel] = jw;
        if (lane == sel) myj = jw;
#pragma unroll
        for (int tt = 0; tt < 4; ++tt) if (key[tt] == m) key[tt] = ~0ull;
    }
    if (lane < KNN) {
        float f0 = x[myj * 3 + 0] - xi0; f0 -= rintf(f0);
        float f1 = x[myj * 3 + 1] - xi1; f1 -= rintf(f1);
        float f2 = x[myj * 3 + 2] - xi2; f2 -= rintf(f2);
        float dd = sqrtf(f0 * f0 + f1 * f1 + f2 * f2);
        float inv = 1.f / (dd + 1e-12f);
        int e = a * KNN + lane;
        u0[e * 3 + 0] = f0 * inv; u0[e * 3 + 1] = f1 * inv; u0[e * 3 + 2] = f2 * inv;
        dist0[e] = dd;
    }
}

// ---------------- fused layer (split-MFMA): dist + agg + W2 GEMM + residual (+pq) + next W1 GEMM ----------------
// grid 512 x 256; block = 8 atoms. Weights read as b-frags directly from global (L2-resident).
// M=8 uses half the 16x16 MFMA tile; rows 8-15 garbage, never stored.
__global__ __launch_bounds__(256, 2) void layer_kernel(
    const float* __restrict__ hW, const int* __restrict__ idxb,
    const float* __restrict__ dist0,
    const float* __restrict__ x, const float* __restrict__ geo, int use_geo,
    const float* __restrict__ wl, const float* __restrict__ b1,
    const short* __restrict__ W2h, const short* __restrict__ W2l,
    const float* __restrict__ b2,
    const short* __restrict__ W1nh, const short* __restrict__ W1nl,
    float* __restrict__ hWout,
    float* __restrict__ h, int write_h,
    const float* __restrict__ we_a, const float* __restrict__ we_p,
    float* __restrict__ p, float* __restrict__ q)
{
    __shared__ short sAggH[16 * 136]; // agg bf16 hi [m][k] (rows 8-15 unused)
    __shared__ short sAggL[16 * 136]; // agg bf16 lo
    __shared__ short sHnH[16 * 136];  // h_new bf16 hi
    __shared__ short sHnL[16 * 136];  // h_new bf16 lo
    __shared__ float sHf[8 * 136];    // h_new fp32 (for p,q)
    __shared__ int   sIdx[8 * KNN];
    __shared__ float sDist[8 * KNN];
    const int t = threadIdx.x;
    const int atom0 = blockIdx.x * 8;
    // phase 1: indices + distances
    if (t < 8 * KNN) {
        int a = atom0 + (t / KNN);
        int j = idxb[atom0 * KNN + t];
        sIdx[t] = j;
        float d;
        if (dist0 != nullptr) {
            d = dist0[atom0 * KNN + t];
        } else {
            float f0 = x[j * 3 + 0] - x[a * 3 + 0]; f0 -= rintf(f0);
            float f1 = x[j * 3 + 1] - x[a * 3 + 1]; f1 -= rintf(f1);
            float f2 = x[j * 3 + 2] - x[a * 3 + 2]; f2 -= rintf(f2);
            const float* c = geo + (a >> 8) * 9;
            float v0 = f0 * c[0] + f1 * c[3] + f2 * c[6];
            float v1 = f0 * c[1] + f1 * c[4] + f2 * c[7];
            float v2 = f0 * c[2] + f1 * c[5] + f2 * c[8];
            d = sqrtf(v0 * v0 + v1 * v1 + v2 * v2);
        }
        sDist[t] = d;
    }
    __syncthreads();
    // phase 2: agg s_a[g] = sum_k silu(hW[j][g] + d*wl[g] + b1[g]) -> bf16 hi/lo
    {
        const int g = t & 127;
        const int sub = t >> 7;
        const float wlg = wl[g];
        const float b1g = b1[g];
#pragma unroll
        for (int rep = 0; rep < 4; ++rep) {
            const int a = rep * 2 + sub;
            float s = 0.f;
#pragma unroll 8
            for (int k = 0; k < KNN; ++k) {
                int j = sIdx[a * KNN + k];
                float v = hW[j * FD + g] + sDist[a * KNN + k] * wlg + b1g;
                s += silu_f(v);
            }
            short hi = f2b(s);
            sAggH[a * 136 + g] = hi;
            sAggL[a * 136 + g] = f2b(s - b2f(hi));
        }
    }
    __syncthreads();
    // phase 3: W2 split-MFMA GEMM (b-frags straight from global)
    const int w = t >> 6, lane = t & 63, quad = lane >> 4, col = lane & 15;
    const int n0 = w * 32;
    f32x4 acc0 = {0.f, 0.f, 0.f, 0.f}, acc1 = {0.f, 0.f, 0.f, 0.f};
#pragma unroll
    for (int ks = 0; ks < 4; ++ks) {
        short8 ah = *(const short8*)&sAggH[col * 136 + ks * 32 + quad * 8];
        short8 al = *(const short8*)&sAggL[col * 136 + ks * 32 + quad * 8];
        short8 bh0 = ldb(W2h, n0 + col, ks, quad);
        short8 bl0 = ldb(W2l, n0 + col, ks, quad);
        short8 bh1 = ldb(W2h, n0 + 16 + col, ks, quad);
        short8 bl1 = ldb(W2l, n0 + 16 + col, ks, quad);
        acc0 = __builtin_amdgcn_mfma_f32_16x16x32_bf16(ah, bh0, acc0, 0, 0, 0);
        acc0 = __builtin_amdgcn_mfma_f32_16x16x32_bf16(ah, bl0, acc0, 0, 0, 0);
        acc0 = __builtin_amdgcn_mfma_f32_16x16x32_bf16(al, bh0, acc0, 0, 0, 0);
        acc1 = __builtin_amdgcn_mfma_f32_16x16x32_bf16(ah, bh1, acc1, 0, 0, 0);
        acc1 = __builtin_amdgcn_mfma_f32_16x16x32_bf16(ah, bl1, acc1, 0, 0, 0);
        acc1 = __builtin_amdgcn_mfma_f32_16x16x32_bf16(al, bh1, acc1, 0, 0, 0);
    }
    // epilogue: residual + silu; write h (optional); sHn hi/lo + sHf fp32
#pragma unroll
    for (int nt = 0; nt < 2; ++nt) {
        int gn = n0 + nt * 16 + col;
        float bb = b2[gn];
        f32x4 av = (nt == 0) ? acc0 : acc1;
#pragma unroll
        for (int r = 0; r < 4; ++r) {
            int row = quad * 4 + r;
            if (row < 8) {
                float o = h[(atom0 + row) * FD + gn] + silu_f(av[r] + bb);
                if (write_h) h[(atom0 + row) * FD + gn] = o;
                short hi = f2b(o);
                sHnH[row * 136 + gn] = hi;
                sHnL[row * 136 + gn] = f2b(o - b2f(hi));
                sHf[row * 136 + gn] = o;
            }
        }
    }
    __syncthreads();
    // phase 4: p,q epilogue (action layers) from fp32 h_new
    if (we_a != nullptr && t < 128) {
        int a = t >> 4, gr = t & 15;
        float pp = 0.f, qq = 0.f;
#pragma unroll
        for (int i = 0; i < 8; ++i) {
            int g = gr + i * 16;
            float hv = sHf[a * 136 + g];
            pp += hv * we_a[g];
            qq += hv * we_p[g];
        }
#pragma unroll
        for (int off = 8; off >= 1; off >>= 1) {
            pp += __shfl_xor(pp, off);
            qq += __shfl_xor(qq, off);
        }
        if (gr == 0) { p[atom0 + a] = pp; q[atom0 + a] = qq; }
    }
    // phase 5: next-layer W1 split-MFMA GEMM on h_new
    if (W1nh != nullptr) {
        f32x4 d0 = {0.f, 0.f, 0.f, 0.f}, d1 = {0.f, 0.f, 0.f, 0.f};
#pragma unroll
        for (int ks = 0; ks < 4; ++ks) {
            short8 ah = *(const short8*)&sHnH[col * 136 + ks * 32 + quad * 8];
            short8 al = *(const short8*)&sHnL[col * 136 + ks * 32 + quad * 8];
            short8 bh0 = ldb(W1nh, n0 + col, ks, quad);
            short8 bl0 = ldb(W1nl, n0 + col, ks, quad);
            short8 bh1 = ldb(W1nh, n0 + 16 + col, ks, quad);
            short8 bl1 = ldb(W1nl, n0 + 16 + col, ks, quad);
            d0 = __builtin_amdgcn_mfma_f32_16x16x32_bf16(ah, bh0, d0, 0, 0, 0);
            d0 = __builtin_amdgcn_mfma_f32_16x16x32_bf16(ah, bl0, d0, 0, 0, 0);
            d0 = __builtin_amdgcn_mfma_f32_16x16x32_bf16(al, bh0, d0, 0, 0, 0);
            d1 = __builtin_amdgcn_mfma_f32_16x16x32_bf16(ah, bh1, d1, 0, 0, 0);
            d1 = __builtin_amdgcn_mfma_f32_16x16x32_bf16(ah, bl1, d1, 0, 0, 0);
            d1 = __builtin_amdgcn_mfma_f32_16x16x32_bf16(al, bh1, d1, 0, 0, 0);
        }
#pragma unroll
        for (int nt = 0; nt < 2; ++nt) {
            int gn = n0 + nt * 16 + col;
            f32x4 av = (nt == 0) ? d0 : d1;
#pragma unroll
            for (int r = 0; r < 4; ++r) {
                int row = quad * 4 + r;
                if (row < 8)
                    hWout[(atom0 + row) * FD + gn] = av[r];
            }
        }
    }
}

// ---------------- per-atom action accumulation (inline vec/u): partials + x_cart ----------------
__global__ __launch_bounds__(256) void accum_kernel(
    const float* __restrict__ p, const float* __restrict__ q,
    const int* __restrict__ idxb, const float* __restrict__ x,
    const float* __restrict__ geo, int use_geo,
    const float* __restrict__ u0b,
    float* __restrict__ part, float* __restrict__ xcart)
{
    const int blk = blockIdx.x;
    const int t = threadIdx.x;
    const int w = t >> 6;
    const int lane = t & 63;
    const int a = blk * 4 + w;
    const int b = a >> 8;
    __shared__ float swe[4][KNN], swp[4][KNN];
    __shared__ float su[4][KNN][3], su0[4][KNN][3], sv[4][KNN][3];
    __shared__ float spart[4][18];
    if (lane < KNN) {
        int e = a * KNN + lane;
        int j = idxb[e];
        swe[w][lane] = tanhf(p[a] + p[j]);
        swp[w][lane] = tanhf(q[a] + q[j]);
        float f0 = x[j * 3 + 0] - x[a * 3 + 0]; f0 -= rintf(f0);
        float f1 = x[j * 3 + 1] - x[a * 3 + 1]; f1 -= rintf(f1);
        float f2 = x[j * 3 + 2] - x[a * 3 + 2]; f2 -= rintf(f2);
        float v0 = f0, v1 = f1, v2 = f2;
        if (use_geo) {
            const float* c = geo + b * 9;
            v0 = f0 * c[0] + f1 * c[3] + f2 * c[6];
            v1 = f0 * c[1] + f1 * c[4] + f2 * c[7];
            v2 = f0 * c[2] + f1 * c[5] + f2 * c[8];
        }
        float dd = sqrtf(v0 * v0 + v1 * v1 + v2 * v2);
        float inv = 1.f / (dd + 1e-12f);
        sv[w][lane][0] = v0; sv[w][lane][1] = v1; sv[w][lane][2] = v2;
        su[w][lane][0] = v0 * inv; su[w][lane][1] = v1 * inv; su[w][lane][2] = v2 * inv;
        su0[w][lane][0] = u0b[e * 3]; su0[w][lane][1] = u0b[e * 3 + 1]; su0[w][lane][2] = u0b[e * 3 + 2];
    }
    __syncthreads();
    float r[21];
#pragma unroll
    for (int i = 0; i < 21; ++i) r[i] = 0.f;
    if (lane < KNN) {
        float wgt = swe[w][lane];
        float ux = su[w][lane][0], uy = su[w][lane][1], uz = su[w][lane][2];
        r[0] = wgt * ux * ux; r[1] = wgt * ux * uy; r[2] = wgt * ux * uz;
        r[3] = wgt * uy * ux; r[4] = wgt * uy * uy; r[5] = wgt * uy * uz;
        r[6] = wgt * uz * ux; r[7] = wgt * uz * uy; r[8] = wgt * uz * uz;
        float wp = swp[w][lane];
        r[18] = wp * sv[w][lane][0]; r[19] = wp * sv[w][lane][1]; r[20] = wp * sv[w][lane][2];
    }
#pragma unroll
    for (int tt = 0; tt < 9; ++tt) {
        int pr = lane + (tt << 6);          // 0..575 = 24*24
        int j = pr / KNN, k = pr - j * KNN;
        float c0x = su0[w][j][1] * su0[w][k][2] - su0[w][j][2] * su0[w][k][1];
        float c0y = su0[w][j][2] * su0[w][k][0] - su0[w][j][0] * su0[w][k][2];
        float c0z = su0[w][j][0] * su0[w][k][1] - su0[w][j][1] * su0[w][k][0];
        float nn2 = c0x * c0x + c0y * c0y + c0z * c0z;
        if (nn2 > 1e-6f) {
            float cx = su[w][j][1] * su[w][k][2] - su[w][j][2] * su[w][k][1];
            float cy = su[w][j][2] * su[w][k][0] - su[w][j][0] * su[w][k][2];
            float cz = su[w][j][0] * su[w][k][1] - su[w][j][1] * su[w][k][0];
            float wt = swe[w][j] * swe[w][k];
            r[9]  += wt * cx * cx; r[10] += wt * cx * cy; r[11] += wt * cx * cz;
            r[12] += wt * cy * cx; r[13] += wt * cy * cy; r[14] += wt * cy * cz;
            r[15] += wt * cz * cx; r[16] += wt * cz * cy; r[17] += wt * cz * cz;
        }
    }
#pragma unroll
    for (int off = 32; off > 0; off >>= 1)
#pragma unroll
        for (int i = 0; i < 21; ++i) r[i] += __shfl_down(r[i], off);
    if (lane == 0) {
#pragma unroll
        for (int i = 0; i < 18; ++i) spart[w][i] = r[i];
        xcart[a * 3 + 0] = EPSA * r[18];
        xcart[a * 3 + 1] = EPSA * r[19];
        xcart[a * 3 + 2] = EPSA * r[20];
    }
    __syncthreads();
    if (t < 18)
        part[blk * 18 + t] = spart[0][t] + spart[1][t] + spart[2][t] + spart[3][t];
}

// ---------------- fused rho + pos ----------------
__global__ __launch_bounds__(256) void rho_pos_kernel(const float* __restrict__ part,
    const float* __restrict__ xcart,
    float* __restrict__ rho, float* __restrict__ geo,
    float* __restrict__ x, float* __restrict__ traj,
    float* __restrict__ out, int first, int last)
{
    const int b = blockIdx.x;
    const int t = threadIdx.x;
    __shared__ float sIV[9];
    if (t < 64) {
        float r[18];
#pragma unroll
        for (int i = 0; i < 18; ++i) r[i] = part[(b * 64 + t) * 18 + i];
#pragma unroll
        for (int off = 32; off > 0; off >>= 1)
#pragma unroll
            for (int i = 0; i < 18; ++i) r[i] += __shfl_down(r[i], off);
        if (t == 0) {
            float A[9];
#pragma unroll
            for (int i = 0; i < 9; ++i) {
                float strain = r[i] / 6144.f;           // NAT*K
                float tri = r[9 + i] / 147456.f;        // NAT*K*K
                A[i] = ((i == 0 || i == 4 || i == 8) ? 1.f : 0.f) + EPSA * (strain + tri);
            }
            float N[9], IV[9];
            if (first) {
#pragma unroll
                for (int i = 0; i < 9; ++i) { N[i] = A[i]; IV[i] = (i == 0 || i == 4 || i == 8) ? 1.f : 0.f; }
            } else {
                float R[9], G[9];
#pragma unroll
                for (int i = 0; i < 9; ++i) { R[i] = rho[b * 9 + i]; G[i] = geo[b * 9 + i]; }
#pragma unroll
                for (int i = 0; i < 3; ++i)
#pragma unroll
                    for (int k = 0; k < 3; ++k)
                        N[i * 3 + k] = A[i * 3] * R[k] + A[i * 3 + 1] * R[3 + k] + A[i * 3 + 2] * R[6 + k];
                float det = G[0] * (G[4] * G[8] - G[5] * G[7])
                          - G[1] * (G[3] * G[8] - G[5] * G[6])
                          + G[2] * (G[3] * G[7] - G[4] * G[6]);
                float id = 1.f / det;
                IV[0] = (G[4] * G[8] - G[5] * G[7]) * id;
                IV[1] = (G[2] * G[7] - G[1] * G[8]) * id;
                IV[2] = (G[1] * G[5] - G[2] * G[4]) * id;
                IV[3] = (G[5] * G[6] - G[3] * G[8]) * id;
                IV[4] = (G[0] * G[8] - G[2] * G[6]) * id;
                IV[5] = (G[2] * G[3] - G[0] * G[5]) * id;
                IV[6] = (G[3] * G[7] - G[4] * G[6]) * id;
                IV[7] = (G[1] * G[6] - G[0] * G[7]) * id;
                IV[8] = (G[0] * G[4] - G[1] * G[3]) * id;
            }
#pragma unroll
            for (int i = 0; i < 9; ++i) {
                sIV[i] = IV[i];
                rho[b * 9 + i] = N[i];
                if (!last) geo[b * 9 + i] = N[i];
                else out[NATOMS * 3 + b * 9 + i] = N[i];
            }
        }
    }
    __syncthreads();
    for (int d = t; d < NATS * 3; d += 256) {
        int al = d / 3, dim = d - al * 3;
        int ga = b * NATS + al;
        int gi = ga * 3 + dim;
        float c0 = xcart[ga * 3 + 0], c1 = xcart[ga * 3 + 1], c2 = xcart[ga * 3 + 2];
        float tj = traj[gi] + xcart[gi];
        if (!last) {
            float xf = c0 * sIV[0 + dim] + c1 * sIV[3 + dim] + c2 * sIV[6 + dim];
            x[gi] += xf;
            traj[gi] = tj;
        } else {
            out[gi] = tj;
        }
    }
}

extern "C" void kernel_launch(void* const* d_in, const int* in_sizes, int n_in,
                              void* d_out, int out_size, void* d_ws, size_t ws_size,
                              hipStream_t stream)
{
    (void)in_sizes; (void)n_in; (void)out_size; (void)ws_size;
    const float* in_x = (const float*)d_in[1];
    const int*   z    = (const int*)d_in[2];
    const float* emb  = (const float*)d_in[4];
    const float* mW1  = (const float*)d_in[5];
    const float* mb1  = (const float*)d_in[6];
    const float* mW2  = (const float*)d_in[7];
    const float* mb2  = (const float*)d_in[8];
    const float* uW1  = (const float*)d_in[9];
    const float* ub1  = (const float*)d_in[10];
    const float* uW2  = (const float*)d_in[11];
    const float* ub2  = (const float*)d_in[12];
    const float* awe  = (const float*)d_in[13];
    const float* pwe  = (const float*)d_in[14];
    float* out = (float*)d_out;

    // workspace carve (units of 4 B)
    char* wsb = (char*)d_ws;
    size_t off = 0;
    auto carve = [&](size_t elems) {
        void* ptr = wsb + off;
        off += (elems * 4 + 255) & ~(size_t)255;
        return ptr;
    };
    float* traj  = (float*)carve(NATOMS * 3);
    float* part  = (float*)carve(1024 * 18);
    float* x     = (float*)carve(NATOMS * 3);
    float* xcart = (float*)carve(NATOMS * 3);
    float* p     = (float*)carve(NATOMS);
    float* q     = (float*)carve(NATOMS);
    float* rho   = (float*)carve(NB * 9);
    float* geo   = (float*)carve(NB * 9);
    float* u0    = (float*)carve(NEDGE * 3);
    float* dist0 = (float*)carve(NEDGE);
    float* h     = (float*)carve(NATOMS * FD);
    float* hWa   = (float*)carve(NATOMS * FD);
    float* hWb   = (float*)carve(NATOMS * FD);
    int*   idx   = (int*)carve(NEDGE);
    short* wth   = (short*)carve(16 * 16384 / 2);   // 16 bf16 hi matrices [n][k]
    short* wtl   = (short*)carve(16 * 16384 / 2);   // 16 bf16 lo matrices [n][k]

    auto WH = [&](int m) { return wth + m * 16384; };
    auto WL = [&](int m) { return wtl + m * 16384; };
    // m: 0-3 mpnn W1, 4-7 mpnn W2, 8-11 upd W1, 12-15 upd W2

    prep_kernel<<<1024, 256, 0, stream>>>(mW1, mW2, uW1, uW2, wth, wtl);
    init_kernel<<<256, 256, 0, stream>>>(in_x, z, emb, WH(0), WL(0), x, traj, h, hWa);
    knn_kernel<<<NATOMS, 64, 0, stream>>>(x, idx, u0, dist0);

    float* hw_in = hWa;
    float* hw_out = hWb;

    // message-passing layers (identity geometry, x fixed -> dist0 reuse)
    for (int l = 0; l < 4; ++l) {
        int w1n = (l < 3) ? (l + 1) : 8;
        layer_kernel<<<512, 256, 0, stream>>>(hw_in, idx, dist0, x, geo, 0,
            mW1 + l * 129 * 128 + 128 * 128, mb1 + l * 128,
            WH(4 + l), WL(4 + l), mb2 + l * 128,
            WH(w1n), WL(w1n), hw_out, h, 1,
            nullptr, nullptr, nullptr, nullptr);
        float* tmp = hw_in; hw_in = hw_out; hw_out = tmp;
    }
    // action layers
    for (int l = 0; l < 4; ++l) {
        const short* W1nh = (l < 3) ? WH(9 + l) : nullptr;
        const short* W1nl = (l < 3) ? WL(9 + l) : nullptr;
        const float* d0 = (l == 0) ? dist0 : nullptr;
        layer_kernel<<<512, 256, 0, stream>>>(hw_in, idx, d0, x, geo, (l > 0) ? 1 : 0,
            uW1 + l * 129 * 128 + 128 * 128, ub1 + l * 128,
            WH(12 + l), WL(12 + l), ub2 + l * 128,
            W1nh, W1nl, hw_out, h, (l < 3) ? 1 : 0,
            awe + l * 128, pwe + l * 128, p, q);
        float* tmp = hw_in; hw_in = hw_out; hw_out = tmp;
        accum_kernel<<<1024, 256, 0, stream>>>(p, q, idx, x, geo, (l > 0) ? 1 : 0,
            u0, part, xcart);
        rho_pos_kernel<<<NB, 256, 0, stream>>>(part, xcart, rho, geo, x, traj, out,
            (l == 0) ? 1 : 0, (l == 3) ? 1 : 0);
    }
}